// Round 1
// baseline (803.969 us; speedup 1.0000x reference)
//
#include <hip/hip_runtime.h>
#include <hip/hip_bf16.h>
#include <stdint.h>

// ---------------------------------------------------------------------------
// RegressionNet: cost-volume + 3x conv-BN-relu + 2x FC, bf16 MFMA pipeline.
// ---------------------------------------------------------------------------

typedef unsigned short ushort_t;
typedef __attribute__((ext_vector_type(8))) short     bf16x8;
typedef __attribute__((ext_vector_type(8))) unsigned short u16x8;
typedef __attribute__((ext_vector_type(4))) unsigned short u16x4;
typedef __attribute__((ext_vector_type(4))) float     f32x4;

#define NB   64      // batch
#define NC   256     // feature channels
#define NP   256     // H*W
#define KCV  256     // cost-volume K
#define NUV  2304    // 48*48 padded positions
#define DD   1089    // 33*33
#define KP1  1152    // padded cin for conv1 (1089 -> 18*64)
#define NOUT 512
#define NROWS 16384  // B*H*W
#define KFC  131072  // 512*256
#define NF   1024

__device__ __forceinline__ unsigned short f2bf(float x) {
  union { float f; unsigned u; } c; c.f = x;
  unsigned r = c.u + 0x7FFFu + ((c.u >> 16) & 1u);
  return (unsigned short)(r >> 16);
}

__device__ __forceinline__ void gl_lds16(const void* g, void* l) {
  __builtin_amdgcn_global_load_lds(
      (const __attribute__((address_space(1))) unsigned int*)g,
      (__attribute__((address_space(3))) unsigned int*)l, 16, 0, 0);
}

__device__ __forceinline__ f32x4 mfma16(bf16x8 a, bf16x8 b, f32x4 c) {
  return __builtin_amdgcn_mfma_f32_16x16x32_bf16(a, b, c, 0, 0, 0);
}

// ---------------------------------------------------------------------------
// l2-normalize over channels; write pos-major bf16 [b][pos][c].
// grid (64, 2), block 256 (thread = pos).
// ---------------------------------------------------------------------------
__global__ __launch_bounds__(256) void l2norm_t(
    const float* __restrict__ f1, const float* __restrict__ f2,
    ushort_t* __restrict__ AT, ushort_t* __restrict__ N2T)
{
  const float* src = blockIdx.y ? f2 : f1;
  ushort_t*    dst = blockIdx.y ? N2T : AT;
  const int b = blockIdx.x, t = threadIdx.x;
  const float* sb = src + (size_t)b * NC * NP;
  float sq = 0.f;
  for (int c = 0; c < NC; ++c) { float v = sb[c * NP + t]; sq += v * v; }
  float sc = 1.f / fmaxf(sqrtf(sq), 1e-12f);
  ushort_t* db = dst + ((size_t)b * NP + t) * NC;
  for (int c = 0; c < NC; ++c) { float v = sb[c * NP + t]; db[c] = f2bf(v * sc); }
}

// ---------------------------------------------------------------------------
// Pack conv weights (OUT, Cin, 3, 3) fp32 -> [tap][out][cin(pad Kp)] bf16.
// ---------------------------------------------------------------------------
__global__ __launch_bounds__(256) void pack_w(
    const float* __restrict__ W, ushort_t* __restrict__ Wp,
    int Cin, int Kp, int total)
{
  int idx = blockIdx.x * 256 + threadIdx.x;
  if (idx >= total) return;
  int o   = idx / (Cin * 9);
  int rem = idx - o * (Cin * 9);
  int cin = rem / 9;
  int tap = rem - cin * 9;
  Wp[((size_t)tap * NOUT + o) * Kp + cin] = f2bf(W[idx]);
}

// ---------------------------------------------------------------------------
// Cost volume: per-b GEMM (pos x uv over channels), band-gather epilogue.
// grid (18, 2, 64), block 256 = 4 waves; tile 128x128, BK=64.
// ---------------------------------------------------------------------------
__global__ __launch_bounds__(256) void cv_gemm(
    const ushort_t* __restrict__ AT,   // [B][256][256]
    const ushort_t* __restrict__ N2T,  // [B][256][256]
    ushort_t* __restrict__ costT,      // [B][256][1152]
    const ushort_t* __restrict__ zerot)
{
  __shared__ ushort_t As[128 * 64];
  __shared__ ushort_t Bs[128 * 64];
  const int tid = threadIdx.x, lane = tid & 63, wave = tid >> 6;
  const int wr = wave >> 1, wc = wave & 1;
  const int la = lane & 15, lb = lane >> 4;
  const int b  = blockIdx.z;
  const int m0 = blockIdx.y * 128;
  const int n0 = blockIdx.x * 128;

  f32x4 acc[4][4];
#pragma unroll
  for (int i = 0; i < 4; ++i)
#pragma unroll
    for (int j = 0; j < 4; ++j) acc[i][j] = (f32x4){0.f, 0.f, 0.f, 0.f};

  const ushort_t* srcA[4];
  const ushort_t* srcB[4];
#pragma unroll
  for (int s = 0; s < 4; ++s) {
    int idx = tid + (s << 8);
    int row = idx >> 3, c16 = idx & 7;
    srcA[s] = AT + ((size_t)b * NP + m0 + row) * NC + c16 * 8;
    int uv = n0 + row;
    int u = uv / 48, v = uv - u * 48;
    int oi = u - 16, oj = v - 16;
    bool val = ((unsigned)oi < 16u) & ((unsigned)oj < 16u);
    srcB[s] = val ? (N2T + ((size_t)b * NP + oi * 16 + oj) * NC + c16 * 8)
                  : (const ushort_t*)0;
  }

  for (int kc = 0; kc < KCV; kc += 64) {
#pragma unroll
    for (int s = 0; s < 4; ++s) {
      int idx = tid + (s << 8);
      gl_lds16(srcA[s] + kc, &As[idx * 8]);
      const ushort_t* g = srcB[s] ? srcB[s] + kc : zerot;
      gl_lds16(g, &Bs[idx * 8]);
    }
    __syncthreads();
#pragma unroll
    for (int kk = 0; kk < 2; ++kk) {
      bf16x8 af[4], bfv[4];
#pragma unroll
      for (int mi = 0; mi < 4; ++mi)
        af[mi] = *(const bf16x8*)&As[(wr * 64 + mi * 16 + la) * 64 + kk * 32 + lb * 8];
#pragma unroll
      for (int ni = 0; ni < 4; ++ni)
        bfv[ni] = *(const bf16x8*)&Bs[(wc * 64 + ni * 16 + la) * 64 + kk * 32 + lb * 8];
#pragma unroll
      for (int mi = 0; mi < 4; ++mi)
#pragma unroll
        for (int ni = 0; ni < 4; ++ni)
          acc[mi][ni] = mfma16(af[mi], bfv[ni], acc[mi][ni]);
    }
    __syncthreads();
  }

  const float sc = 1.f / 256.f;
#pragma unroll
  for (int ni = 0; ni < 4; ++ni) {
    int uv = n0 + wc * 64 + ni * 16 + la;
    int u = uv / 48, v = uv - u * 48;
#pragma unroll
    for (int mi = 0; mi < 4; ++mi) {
      int ij = m0 + wr * 64 + mi * 16 + lb * 4;
#pragma unroll
      for (int r = 0; r < 4; ++r) {
        int ijr = ij + r;
        int i = ijr >> 4, j = ijr & 15;
        int dy = u - i, dx = v - j;
        if ((unsigned)dy < 33u && (unsigned)dx < 33u) {
          float vv = acc[mi][ni][r] * sc;
          vv = vv > 0.f ? vv : 0.01f * vv;
          costT[((size_t)b * NP + ijr) * KP1 + dy * 33 + dx] = f2bf(vv);
        }
      }
    }
  }
}

// ---------------------------------------------------------------------------
// Conv 3x3 as tap-decomposed GEMM. X: [16384][K] bf16 (pos-major),
// Wp: [9][512][K] bf16, Y: [16384][512] fp32 (+bias).
// grid (4, 128), block 256; tile 128x128, BK=64.
// ---------------------------------------------------------------------------
__global__ __launch_bounds__(256) void conv_gemm(
    const ushort_t* __restrict__ X, const ushort_t* __restrict__ Wp,
    const float* __restrict__ bias, float* __restrict__ Y,
    int K, const ushort_t* __restrict__ zerot)
{
  __shared__ ushort_t As[128 * 64];
  __shared__ ushort_t Bs[128 * 64];
  const int tid = threadIdx.x, lane = tid & 63, wave = tid >> 6;
  const int wr = wave >> 1, wc = wave & 1;
  const int la = lane & 15, lb = lane >> 4;
  const int n0 = blockIdx.x * 128;
  const int m0 = blockIdx.y * 128;
  const int b  = m0 >> 8;
  const int ij0 = m0 & 255;

  f32x4 acc[4][4];
#pragma unroll
  for (int i = 0; i < 4; ++i)
#pragma unroll
    for (int j = 0; j < 4; ++j) acc[i][j] = (f32x4){0.f, 0.f, 0.f, 0.f};

  int rowA[4], c16A[4];
#pragma unroll
  for (int s = 0; s < 4; ++s) {
    int idx = tid + (s << 8);
    rowA[s] = idx >> 3; c16A[s] = idx & 7;
  }

  for (int tap = 0; tap < 9; ++tap) {
    const int ty = tap / 3 - 1, tx = tap - (tap / 3) * 3 - 1;
    const ushort_t* srcA[4];
    const ushort_t* srcB[4];
    const ushort_t* wbase = Wp + (size_t)tap * NOUT * K;
#pragma unroll
    for (int s = 0; s < 4; ++s) {
      int ij = ij0 + rowA[s];
      int i2 = (ij >> 4) + ty, j2 = (ij & 15) + tx;
      bool val = ((unsigned)i2 < 16u) & ((unsigned)j2 < 16u);
      srcA[s] = val ? (X + (size_t)(b * NP + (i2 << 4) + j2) * K + c16A[s] * 8)
                    : (const ushort_t*)0;
      srcB[s] = wbase + (size_t)(n0 + rowA[s]) * K + c16A[s] * 8;
    }

    for (int kc = 0; kc < K; kc += 64) {
#pragma unroll
      for (int s = 0; s < 4; ++s) {
        int idx = tid + (s << 8);
        const ushort_t* g = srcA[s] ? srcA[s] + kc : zerot;
        gl_lds16(g, &As[idx * 8]);
        gl_lds16(srcB[s] + kc, &Bs[idx * 8]);
      }
      __syncthreads();
#pragma unroll
      for (int kk = 0; kk < 2; ++kk) {
        bf16x8 af[4], bfv[4];
#pragma unroll
        for (int mi = 0; mi < 4; ++mi)
          af[mi] = *(const bf16x8*)&As[(wr * 64 + mi * 16 + la) * 64 + kk * 32 + lb * 8];
#pragma unroll
        for (int ni = 0; ni < 4; ++ni)
          bfv[ni] = *(const bf16x8*)&Bs[(wc * 64 + ni * 16 + la) * 64 + kk * 32 + lb * 8];
#pragma unroll
        for (int mi = 0; mi < 4; ++mi)
#pragma unroll
          for (int ni = 0; ni < 4; ++ni)
            acc[mi][ni] = mfma16(af[mi], bfv[ni], acc[mi][ni]);
      }
      __syncthreads();
    }
  }

#pragma unroll
  for (int ni = 0; ni < 4; ++ni) {
    int col = n0 + wc * 64 + ni * 16 + la;
    float bv = bias[col];
#pragma unroll
    for (int mi = 0; mi < 4; ++mi) {
      int row = m0 + wr * 64 + mi * 16 + lb * 4;
#pragma unroll
      for (int r = 0; r < 4; ++r)
        Y[(size_t)(row + r) * NOUT + col] = acc[mi][ni][r] + bv;
    }
  }
}

// ---------------------------------------------------------------------------
// BN stats: per-channel sum / sumsq over 16384 rows. grid 128, block 256.
// st layout: [sum 512][sumsq 512], pre-zeroed.
// ---------------------------------------------------------------------------
__global__ __launch_bounds__(256) void bn_stat(
    const float* __restrict__ Y, float* __restrict__ st)
{
  const int t = threadIdx.x;
  const float* base = Y + (size_t)blockIdx.x * 128 * NOUT;
  float s0 = 0.f, q0 = 0.f, s1 = 0.f, q1 = 0.f;
  for (int r = 0; r < 128; ++r) {
    float a = base[r * NOUT + t];
    float c = base[r * NOUT + t + 256];
    s0 += a; q0 += a * a; s1 += c; q1 += c * c;
  }
  atomicAdd(&st[t], s0);         atomicAdd(&st[t + 256], s1);
  atomicAdd(&st[512 + t], q0);   atomicAdd(&st[512 + t + 256], q1);
}

// ---------------------------------------------------------------------------
// BN apply + relu + bf16 cast. mode 0: write [m][c]; mode 1: write FC layout
// Xf[b][c*256+ij]. grid 8192, block 256, 4 elems/thread.
// ---------------------------------------------------------------------------
__global__ __launch_bounds__(256) void bn_apply(
    const float* __restrict__ Y, const float* __restrict__ st,
    const float* __restrict__ g, const float* __restrict__ be,
    ushort_t* __restrict__ Xo, int mode)
{
  const int idx = blockIdx.x * 256 + threadIdx.x;
  const float4 y = *(const float4*)(Y + (size_t)idx * 4);
  const int m = (idx * 4) >> 9, c0 = (idx * 4) & 511;
  const float yv[4] = {y.x, y.y, y.z, y.w};
  ushort_t o[4];
#pragma unroll
  for (int q = 0; q < 4; ++q) {
    int c = c0 + q;
    float mu  = st[c] * (1.f / 16384.f);
    float var = st[512 + c] * (1.f / 16384.f) - mu * mu;
    float s = rsqrtf(var + 1e-5f) * g[c];
    float v = fmaxf((yv[q] - mu) * s + be[c], 0.f);
    o[q] = f2bf(v);
  }
  if (mode == 0) {
    u16x4 pk = {o[0], o[1], o[2], o[3]};
    *(u16x4*)(Xo + (size_t)idx * 4) = pk;
  } else {
    int b = m >> 8, ij = m & 255;
#pragma unroll
    for (int q = 0; q < 4; ++q)
      Xo[(size_t)b * KFC + (size_t)(c0 + q) * NP + ij] = o[q];
  }
}

// ---------------------------------------------------------------------------
// FC1: (64 x 131072) bf16 @ (1024 x 131072)^T fp32->bf16, split-K atomics.
// grid (16, 32), block 256; partial 64x64 per block.
// ---------------------------------------------------------------------------
__device__ __forceinline__ u16x8 pack8(float4 a, float4 b) {
  u16x8 r;
  r[0] = f2bf(a.x); r[1] = f2bf(a.y); r[2] = f2bf(a.z); r[3] = f2bf(a.w);
  r[4] = f2bf(b.x); r[5] = f2bf(b.y); r[6] = f2bf(b.z); r[7] = f2bf(b.w);
  return r;
}

__global__ __launch_bounds__(256) void fc1_gemm(
    const ushort_t* __restrict__ Xf, const float* __restrict__ Wf1,
    float* __restrict__ hacc)
{
  __shared__ ushort_t As[64 * 64];
  __shared__ ushort_t Bs[64 * 64];
  const int tid = threadIdx.x, lane = tid & 63, wave = tid >> 6;
  const int la = lane & 15, lb = lane >> 4;
  const int f0 = blockIdx.x * 64;
  const int k0 = blockIdx.y * 4096;

  f32x4 acc[4];
#pragma unroll
  for (int i = 0; i < 4; ++i) acc[i] = (f32x4){0.f, 0.f, 0.f, 0.f};

  const ushort_t* xrow[2];
#pragma unroll
  for (int s = 0; s < 2; ++s) {
    int idx = tid + (s << 8);
    xrow[s] = Xf + (size_t)(idx >> 3) * KFC + k0 + (idx & 7) * 8;
  }
  const int brow = tid >> 2, kseg = (tid & 3) * 16;
  const float* wrow = Wf1 + (size_t)(f0 + brow) * KFC + k0 + kseg;

  for (int kc = 0; kc < 4096; kc += 64) {
#pragma unroll
    for (int s = 0; s < 2; ++s) {
      int idx = tid + (s << 8);
      gl_lds16(xrow[s] + kc, &As[idx * 8]);
    }
    float4 w0 = *(const float4*)(wrow + kc);
    float4 w1 = *(const float4*)(wrow + kc + 4);
    float4 w2 = *(const float4*)(wrow + kc + 8);
    float4 w3 = *(const float4*)(wrow + kc + 12);
    *(u16x8*)&Bs[brow * 64 + kseg]     = pack8(w0, w1);
    *(u16x8*)&Bs[brow * 64 + kseg + 8] = pack8(w2, w3);
    __syncthreads();
#pragma unroll
    for (int kk = 0; kk < 2; ++kk) {
      bf16x8 bfv = *(const bf16x8*)&Bs[(wave * 16 + la) * 64 + kk * 32 + lb * 8];
#pragma unroll
      for (int mi = 0; mi < 4; ++mi) {
        bf16x8 av = *(const bf16x8*)&As[(mi * 16 + la) * 64 + kk * 32 + lb * 8];
        acc[mi] = mfma16(av, bfv, acc[mi]);
      }
    }
    __syncthreads();
  }

#pragma unroll
  for (int mi = 0; mi < 4; ++mi) {
    int row = mi * 16 + lb * 4;
#pragma unroll
    for (int r = 0; r < 4; ++r)
      atomicAdd(&hacc[(size_t)(row + r) * NF + f0 + wave * 16 + la], acc[mi][r]);
  }
}

// ---------------------------------------------------------------------------
// FC2 + bias/relu on FC1 output. grid 64 (per batch), block 256.
// ---------------------------------------------------------------------------
__global__ __launch_bounds__(256) void fc2_out(
    const float* __restrict__ hacc, const float* __restrict__ bf1,
    const float* __restrict__ Wf2, const float* __restrict__ bf2,
    float* __restrict__ out)
{
  const int b = blockIdx.x, tid = threadIdx.x;
  float a[8];
#pragma unroll
  for (int o = 0; o < 8; ++o) a[o] = 0.f;
  for (int f = tid; f < NF; f += 256) {
    float hv = fmaxf(hacc[(size_t)b * NF + f] + bf1[f], 0.f);
#pragma unroll
    for (int o = 0; o < 8; ++o) a[o] += hv * Wf2[o * NF + f];
  }
  __shared__ float red[8][256];
#pragma unroll
  for (int o = 0; o < 8; ++o) red[o][tid] = a[o];
  __syncthreads();
  for (int s = 128; s > 0; s >>= 1) {
    if (tid < s) {
#pragma unroll
      for (int o = 0; o < 8; ++o) red[o][tid] += red[o][tid + s];
    }
    __syncthreads();
  }
  if (tid < 8) out[b * 8 + tid] = red[tid][0] + bf2[tid];
}

// ---------------------------------------------------------------------------
extern "C" void kernel_launch(void* const* d_in, const int* in_sizes, int n_in,
                              void* d_out, int out_size, void* d_ws, size_t ws_size,
                              hipStream_t stream) {
  const float* f1  = (const float*)d_in[0];
  const float* f2  = (const float*)d_in[1];
  const float* W1  = (const float*)d_in[2];
  const float* b1  = (const float*)d_in[3];
  const float* g1  = (const float*)d_in[4];
  const float* be1 = (const float*)d_in[5];
  const float* W2  = (const float*)d_in[6];
  const float* b2  = (const float*)d_in[7];
  const float* g2  = (const float*)d_in[8];
  const float* be2 = (const float*)d_in[9];
  const float* W3  = (const float*)d_in[10];
  const float* b3  = (const float*)d_in[11];
  const float* g3  = (const float*)d_in[12];
  const float* be3 = (const float*)d_in[13];
  const float* Wf1 = (const float*)d_in[14];
  const float* bf1 = (const float*)d_in[15];
  const float* Wf2 = (const float*)d_in[16];
  const float* bf2 = (const float*)d_in[17];
  float* out = (float*)d_out;

  char* ws = (char*)d_ws;
  size_t off = 0;
  auto alloc = [&](size_t bytes) -> void* {
    void* p = ws + off;
    off += (bytes + 255) & ~(size_t)255;
    return p;
  };

  ushort_t* zerot = (ushort_t*)alloc(256);
  float* st1  = (float*)alloc(1024 * 4);
  float* st2  = (float*)alloc(1024 * 4);
  float* st3  = (float*)alloc(1024 * 4);
  float* hacc = (float*)alloc((size_t)NB * NF * 4);
  const size_t zero_bytes = off;

  const size_t SZ_AT   = (size_t)NB * NP * NC * 2;
  const size_t SZ_COST = (size_t)NB * NP * KP1 * 2;
  const size_t SZ_WP1  = (size_t)9 * NOUT * KP1 * 2;
  const size_t SZ_WP23 = (size_t)9 * NOUT * 512 * 2;
  ushort_t* AT    = (ushort_t*)alloc(SZ_AT);
  ushort_t* N2T   = (ushort_t*)alloc(SZ_AT);
  ushort_t* costT = (ushort_t*)alloc(SZ_COST);
  ushort_t* Wp1   = (ushort_t*)alloc(SZ_WP1);
  ushort_t* Wp2   = (ushort_t*)alloc(SZ_WP23);
  ushort_t* Wp3   = (ushort_t*)alloc(SZ_WP23);
  float*    Ybuf  = (float*)alloc((size_t)NROWS * NOUT * 4);
  ushort_t* Xbuf  = (ushort_t*)alloc((size_t)NROWS * NOUT * 2);
  ushort_t* Xf    = (ushort_t*)alloc((size_t)NB * KFC * 2);

  hipMemsetAsync(ws, 0, zero_bytes, stream);
  hipMemsetAsync(costT, 0, SZ_COST, stream);
  hipMemsetAsync(Wp1, 0, SZ_WP1, stream);

  l2norm_t<<<dim3(64, 2), 256, 0, stream>>>(f1, f2, AT, N2T);

  pack_w<<<(512 * 1089 * 9 + 255) / 256, 256, 0, stream>>>(W1, Wp1, 1089, KP1, 512 * 1089 * 9);
  pack_w<<<(512 * 512 * 9 + 255) / 256, 256, 0, stream>>>(W2, Wp2, 512, 512, 512 * 512 * 9);
  pack_w<<<(512 * 512 * 9 + 255) / 256, 256, 0, stream>>>(W3, Wp3, 512, 512, 512 * 512 * 9);

  cv_gemm<<<dim3(18, 2, 64), 256, 0, stream>>>(AT, N2T, costT, zerot);

  conv_gemm<<<dim3(4, 128), 256, 0, stream>>>(costT, Wp1, b1, Ybuf, KP1, zerot);
  bn_stat<<<128, 256, 0, stream>>>(Ybuf, st1);
  bn_apply<<<8192, 256, 0, stream>>>(Ybuf, st1, g1, be1, Xbuf, 0);

  conv_gemm<<<dim3(4, 128), 256, 0, stream>>>(Xbuf, Wp2, b2, Ybuf, 512, zerot);
  bn_stat<<<128, 256, 0, stream>>>(Ybuf, st2);
  bn_apply<<<8192, 256, 0, stream>>>(Ybuf, st2, g2, be2, Xbuf, 0);

  conv_gemm<<<dim3(4, 128), 256, 0, stream>>>(Xbuf, Wp3, b3, Ybuf, 512, zerot);
  bn_stat<<<128, 256, 0, stream>>>(Ybuf, st3);
  bn_apply<<<8192, 256, 0, stream>>>(Ybuf, st3, g3, be3, Xf, 1);

  fc1_gemm<<<dim3(16, 32), 256, 0, stream>>>(Xf, Wf1, hacc);
  fc2_out<<<64, 256, 0, stream>>>(hacc, bf1, Wf2, bf2, out);

  (void)in_sizes; (void)n_in; (void)out_size; (void)ws_size;
}

// Round 2
// 752.066 us; speedup vs baseline: 1.0690x; 1.0690x over previous
//
#include <hip/hip_runtime.h>
#include <hip/hip_bf16.h>
#include <stdint.h>

// ---------------------------------------------------------------------------
// RegressionNet: cost-volume + 3x conv-BN-relu + 2x FC, bf16 MFMA pipeline.
// R1: coalesced pack_w, LDS-transpose bn_apply for FC layout, BN stats fused
//     into conv epilogue, XCD swizzle on conv blocks, vectorized l2norm store.
// ---------------------------------------------------------------------------

typedef unsigned short ushort_t;
typedef __attribute__((ext_vector_type(8))) short     bf16x8;
typedef __attribute__((ext_vector_type(8))) unsigned short u16x8;
typedef __attribute__((ext_vector_type(4))) unsigned short u16x4;
typedef __attribute__((ext_vector_type(4))) float     f32x4;

#define NB   64      // batch
#define NC   256     // feature channels
#define NP   256     // H*W
#define KCV  256     // cost-volume K
#define KP1  1152    // padded cin for conv1 (1089 -> 18*64)
#define NOUT 512
#define NROWS 16384  // B*H*W
#define KFC  131072  // 512*256
#define NF   1024

__device__ __forceinline__ unsigned short f2bf(float x) {
  union { float f; unsigned u; } c; c.f = x;
  unsigned r = c.u + 0x7FFFu + ((c.u >> 16) & 1u);
  return (unsigned short)(r >> 16);
}

__device__ __forceinline__ void gl_lds16(const void* g, void* l) {
  __builtin_amdgcn_global_load_lds(
      (const __attribute__((address_space(1))) unsigned int*)g,
      (__attribute__((address_space(3))) unsigned int*)l, 16, 0, 0);
}

__device__ __forceinline__ f32x4 mfma16(bf16x8 a, bf16x8 b, f32x4 c) {
  return __builtin_amdgcn_mfma_f32_16x16x32_bf16(a, b, c, 0, 0, 0);
}

// ---------------------------------------------------------------------------
// l2-normalize over channels; write pos-major bf16 [b][pos][c].
// grid (64, 2), block 256 (thread = pos).
// ---------------------------------------------------------------------------
__global__ __launch_bounds__(256) void l2norm_t(
    const float* __restrict__ f1, const float* __restrict__ f2,
    ushort_t* __restrict__ AT, ushort_t* __restrict__ N2T)
{
  const float* src = blockIdx.y ? f2 : f1;
  ushort_t*    dst = blockIdx.y ? N2T : AT;
  const int b = blockIdx.x, t = threadIdx.x;
  const float* sb = src + (size_t)b * NC * NP;
  float sq = 0.f;
  for (int c = 0; c < NC; ++c) { float v = sb[c * NP + t]; sq += v * v; }
  float sc = 1.f / fmaxf(sqrtf(sq), 1e-12f);
  ushort_t* db = dst + ((size_t)b * NP + t) * NC;
  for (int c0 = 0; c0 < NC; c0 += 8) {
    u16x8 pk;
#pragma unroll
    for (int q = 0; q < 8; ++q) pk[q] = f2bf(sb[(c0 + q) * NP + t] * sc);
    *(u16x8*)(db + c0) = pk;
  }
}

// ---------------------------------------------------------------------------
// Pack conv weights (OUT, Cin, 3, 3) fp32 -> [tap][out][cin(pad Kp)] bf16.
// Output-indexed: writes coalesced, reads stride-36B (L2/L3 resident).
// Also writes zeros into the cin pad (no memset needed).
// ---------------------------------------------------------------------------
__global__ __launch_bounds__(256) void pack_w(
    const float* __restrict__ W, ushort_t* __restrict__ Wp,
    int Cin, int Kp, int total)
{
  int p = blockIdx.x * 256 + threadIdx.x;
  if (p >= total) return;
  int tap = p / (NOUT * Kp);
  int rem = p - tap * (NOUT * Kp);
  int o   = rem / Kp;
  int cin = rem - o * Kp;
  float v = (cin < Cin) ? W[((size_t)o * Cin + cin) * 9 + tap] : 0.f;
  Wp[p] = f2bf(v);
}

// ---------------------------------------------------------------------------
// Cost volume: per-b GEMM (pos x uv over channels), band-gather epilogue.
// grid (18, 2, 64), block 256 = 4 waves; tile 128x128, BK=64.
// ---------------------------------------------------------------------------
__global__ __launch_bounds__(256) void cv_gemm(
    const ushort_t* __restrict__ AT,   // [B][256][256]
    const ushort_t* __restrict__ N2T,  // [B][256][256]
    ushort_t* __restrict__ costT,      // [B][256][1152]
    const ushort_t* __restrict__ zerot)
{
  __shared__ ushort_t As[128 * 64];
  __shared__ ushort_t Bs[128 * 64];
  const int tid = threadIdx.x, lane = tid & 63, wave = tid >> 6;
  const int wr = wave >> 1, wc = wave & 1;
  const int la = lane & 15, lb = lane >> 4;
  const int b  = blockIdx.z;
  const int m0 = blockIdx.y * 128;
  const int n0 = blockIdx.x * 128;

  f32x4 acc[4][4];
#pragma unroll
  for (int i = 0; i < 4; ++i)
#pragma unroll
    for (int j = 0; j < 4; ++j) acc[i][j] = (f32x4){0.f, 0.f, 0.f, 0.f};

  const ushort_t* srcA[4];
  const ushort_t* srcB[4];
#pragma unroll
  for (int s = 0; s < 4; ++s) {
    int idx = tid + (s << 8);
    int row = idx >> 3, c16 = idx & 7;
    srcA[s] = AT + ((size_t)b * NP + m0 + row) * NC + c16 * 8;
    int uv = n0 + row;
    int u = uv / 48, v = uv - u * 48;
    int oi = u - 16, oj = v - 16;
    bool val = ((unsigned)oi < 16u) & ((unsigned)oj < 16u);
    srcB[s] = val ? (N2T + ((size_t)b * NP + oi * 16 + oj) * NC + c16 * 8)
                  : (const ushort_t*)0;
  }

  for (int kc = 0; kc < KCV; kc += 64) {
#pragma unroll
    for (int s = 0; s < 4; ++s) {
      int idx = tid + (s << 8);
      gl_lds16(srcA[s] + kc, &As[idx * 8]);
      const ushort_t* g = srcB[s] ? srcB[s] + kc : zerot;
      gl_lds16(g, &Bs[idx * 8]);
    }
    __syncthreads();
#pragma unroll
    for (int kk = 0; kk < 2; ++kk) {
      bf16x8 af[4], bfv[4];
#pragma unroll
      for (int mi = 0; mi < 4; ++mi)
        af[mi] = *(const bf16x8*)&As[(wr * 64 + mi * 16 + la) * 64 + kk * 32 + lb * 8];
#pragma unroll
      for (int ni = 0; ni < 4; ++ni)
        bfv[ni] = *(const bf16x8*)&Bs[(wc * 64 + ni * 16 + la) * 64 + kk * 32 + lb * 8];
#pragma unroll
      for (int mi = 0; mi < 4; ++mi)
#pragma unroll
        for (int ni = 0; ni < 4; ++ni)
          acc[mi][ni] = mfma16(af[mi], bfv[ni], acc[mi][ni]);
    }
    __syncthreads();
  }

  const float sc = 1.f / 256.f;
#pragma unroll
  for (int ni = 0; ni < 4; ++ni) {
    int uv = n0 + wc * 64 + ni * 16 + la;
    int u = uv / 48, v = uv - u * 48;
#pragma unroll
    for (int mi = 0; mi < 4; ++mi) {
      int ij = m0 + wr * 64 + mi * 16 + lb * 4;
#pragma unroll
      for (int r = 0; r < 4; ++r) {
        int ijr = ij + r;
        int i = ijr >> 4, j = ijr & 15;
        int dy = u - i, dx = v - j;
        if ((unsigned)dy < 33u && (unsigned)dx < 33u) {
          float vv = acc[mi][ni][r] * sc;
          vv = vv > 0.f ? vv : 0.01f * vv;
          costT[((size_t)b * NP + ijr) * KP1 + dy * 33 + dx] = f2bf(vv);
        }
      }
    }
  }
}

// ---------------------------------------------------------------------------
// Conv 3x3 as tap-decomposed GEMM. X: [16384][K] bf16 (pos-major),
// Wp: [9][512][K] bf16, Y: [16384][512] fp32 (+bias).
// grid 512 (XCD-swizzled), block 256; tile 128x128, BK=64.
// Fused BN stats: per-block column sum/sumsq -> atomicAdd into st[1024].
// ---------------------------------------------------------------------------
__global__ __launch_bounds__(256) void conv_gemm(
    const ushort_t* __restrict__ X, const ushort_t* __restrict__ Wp,
    const float* __restrict__ bias, float* __restrict__ Y,
    float* __restrict__ st, int K, const ushort_t* __restrict__ zerot)
{
  __shared__ ushort_t As[128 * 64];
  __shared__ ushort_t Bs[128 * 64];
  __shared__ float sred[128][8];
  __shared__ float qred[128][8];
  const int tid = threadIdx.x, lane = tid & 63, wave = tid >> 6;
  const int wr = wave >> 1, wc = wave & 1;
  const int la = lane & 15, lb = lane >> 4;
  // XCD-aware bijective swizzle: 512 blocks, 8 XCDs, 64 contiguous per XCD.
  const int wg = blockIdx.x;
  const int sw = ((wg & 7) << 6) + (wg >> 3);
  const int n0 = (sw & 3) * 128;
  const int m0 = (sw >> 2) * 128;
  const int b  = m0 >> 8;
  const int ij0 = m0 & 255;

  f32x4 acc[4][4];
#pragma unroll
  for (int i = 0; i < 4; ++i)
#pragma unroll
    for (int j = 0; j < 4; ++j) acc[i][j] = (f32x4){0.f, 0.f, 0.f, 0.f};

  int rowA[4], c16A[4];
#pragma unroll
  for (int s = 0; s < 4; ++s) {
    int idx = tid + (s << 8);
    rowA[s] = idx >> 3; c16A[s] = idx & 7;
  }

  for (int tap = 0; tap < 9; ++tap) {
    const int ty = tap / 3 - 1, tx = tap - (tap / 3) * 3 - 1;
    const ushort_t* srcA[4];
    const ushort_t* srcB[4];
    const ushort_t* wbase = Wp + (size_t)tap * NOUT * K;
#pragma unroll
    for (int s = 0; s < 4; ++s) {
      int ij = ij0 + rowA[s];
      int i2 = (ij >> 4) + ty, j2 = (ij & 15) + tx;
      bool val = ((unsigned)i2 < 16u) & ((unsigned)j2 < 16u);
      srcA[s] = val ? (X + (size_t)(b * NP + (i2 << 4) + j2) * K + c16A[s] * 8)
                    : (const ushort_t*)0;
      srcB[s] = wbase + (size_t)(n0 + rowA[s]) * K + c16A[s] * 8;
    }

    for (int kc = 0; kc < K; kc += 64) {
#pragma unroll
      for (int s = 0; s < 4; ++s) {
        int idx = tid + (s << 8);
        const ushort_t* g = srcA[s] ? srcA[s] + kc : zerot;
        gl_lds16(g, &As[idx * 8]);
        gl_lds16(srcB[s] + kc, &Bs[idx * 8]);
      }
      __syncthreads();
#pragma unroll
      for (int kk = 0; kk < 2; ++kk) {
        bf16x8 af[4], bfv[4];
#pragma unroll
        for (int mi = 0; mi < 4; ++mi)
          af[mi] = *(const bf16x8*)&As[(wr * 64 + mi * 16 + la) * 64 + kk * 32 + lb * 8];
#pragma unroll
        for (int ni = 0; ni < 4; ++ni)
          bfv[ni] = *(const bf16x8*)&Bs[(wc * 64 + ni * 16 + la) * 64 + kk * 32 + lb * 8];
#pragma unroll
        for (int mi = 0; mi < 4; ++mi)
#pragma unroll
          for (int ni = 0; ni < 4; ++ni)
            acc[mi][ni] = mfma16(af[mi], bfv[ni], acc[mi][ni]);
      }
      __syncthreads();
    }
  }

  const int wslot = wr * 4 + lb;
#pragma unroll
  for (int ni = 0; ni < 4; ++ni) {
    int colloc = wc * 64 + ni * 16 + la;
    int col = n0 + colloc;
    float bv = bias[col];
    float s = 0.f, q = 0.f;
#pragma unroll
    for (int mi = 0; mi < 4; ++mi) {
      int row = m0 + wr * 64 + mi * 16 + lb * 4;
#pragma unroll
      for (int r = 0; r < 4; ++r) {
        float v = acc[mi][ni][r] + bv;
        Y[(size_t)(row + r) * NOUT + col] = v;
        s += v; q += v * v;
      }
    }
    sred[colloc][wslot] = s;
    qred[colloc][wslot] = q;
  }
  __syncthreads();
  if (tid < 128) {
    float s = 0.f, q = 0.f;
#pragma unroll
    for (int u = 0; u < 8; ++u) { s += sred[tid][u]; q += qred[tid][u]; }
    atomicAdd(&st[n0 + tid], s);
    atomicAdd(&st[512 + n0 + tid], q);
  }
}

// ---------------------------------------------------------------------------
// BN apply + relu + bf16 cast, same-layout output [m][c].
// grid 8192, block 256, 4 elems/thread.
// ---------------------------------------------------------------------------
__global__ __launch_bounds__(256) void bn_apply(
    const float* __restrict__ Y, const float* __restrict__ st,
    const float* __restrict__ g, const float* __restrict__ be,
    ushort_t* __restrict__ Xo)
{
  const int idx = blockIdx.x * 256 + threadIdx.x;
  const float4 y = *(const float4*)(Y + (size_t)idx * 4);
  const int c0 = (idx * 4) & 511;
  const float yv[4] = {y.x, y.y, y.z, y.w};
  u16x4 pk;
#pragma unroll
  for (int q = 0; q < 4; ++q) {
    int c = c0 + q;
    float mu  = st[c] * (1.f / 16384.f);
    float var = st[512 + c] * (1.f / 16384.f) - mu * mu;
    float s = rsqrtf(var + 1e-5f) * g[c];
    pk[q] = f2bf(fmaxf((yv[q] - mu) * s + be[c], 0.f));
  }
  *(u16x4*)(Xo + (size_t)idx * 4) = pk;
}

// ---------------------------------------------------------------------------
// BN apply + relu + bf16, transposed to FC layout Xf[b][c*256+ij] via LDS
// 64x64 tile. grid (8, 4, 64), block 256. Both global sides coalesced.
// ---------------------------------------------------------------------------
__global__ __launch_bounds__(256) void bn_apply_t(
    const float* __restrict__ Y, const float* __restrict__ st,
    const float* __restrict__ g, const float* __restrict__ be,
    ushort_t* __restrict__ Xf)
{
  __shared__ ushort_t T[64][65];
  const int c0  = blockIdx.x * 64;
  const int ij0 = blockIdx.y * 64;
  const int b   = blockIdx.z;
  const int tid = threadIdx.x;

#pragma unroll
  for (int it = 0; it < 16; ++it) {
    int e = it * 256 + tid;
    int ij = e >> 6, c = e & 63;
    int cg = c0 + c;
    float y = Y[((size_t)(b * NP + ij0 + ij)) * NOUT + cg];
    float mu  = st[cg] * (1.f / 16384.f);
    float var = st[512 + cg] * (1.f / 16384.f) - mu * mu;
    float s = rsqrtf(var + 1e-5f) * g[cg];
    T[ij][c] = f2bf(fmaxf((y - mu) * s + be[cg], 0.f));
  }
  __syncthreads();
#pragma unroll
  for (int it = 0; it < 16; ++it) {
    int e = it * 256 + tid;
    int cr = e >> 6, ijc = e & 63;
    Xf[(size_t)b * KFC + (size_t)(c0 + cr) * NP + ij0 + ijc] = T[ijc][cr];
  }
}

// ---------------------------------------------------------------------------
// FC1: (64 x 131072) bf16 @ (1024 x 131072)^T fp32->bf16, split-K atomics.
// grid (16, 32), block 256; partial 64x64 per block.
// ---------------------------------------------------------------------------
__device__ __forceinline__ u16x8 pack8(float4 a, float4 b) {
  u16x8 r;
  r[0] = f2bf(a.x); r[1] = f2bf(a.y); r[2] = f2bf(a.z); r[3] = f2bf(a.w);
  r[4] = f2bf(b.x); r[5] = f2bf(b.y); r[6] = f2bf(b.z); r[7] = f2bf(b.w);
  return r;
}

__global__ __launch_bounds__(256) void fc1_gemm(
    const ushort_t* __restrict__ Xf, const float* __restrict__ Wf1,
    float* __restrict__ hacc)
{
  __shared__ ushort_t As[64 * 64];
  __shared__ ushort_t Bs[64 * 64];
  const int tid = threadIdx.x, lane = tid & 63, wave = tid >> 6;
  const int la = lane & 15, lb = lane >> 4;
  const int f0 = blockIdx.x * 64;
  const int k0 = blockIdx.y * 4096;

  f32x4 acc[4];
#pragma unroll
  for (int i = 0; i < 4; ++i) acc[i] = (f32x4){0.f, 0.f, 0.f, 0.f};

  const ushort_t* xrow[2];
#pragma unroll
  for (int s = 0; s < 2; ++s) {
    int idx = tid + (s << 8);
    xrow[s] = Xf + (size_t)(idx >> 3) * KFC + k0 + (idx & 7) * 8;
  }
  const int brow = tid >> 2, kseg = (tid & 3) * 16;
  const float* wrow = Wf1 + (size_t)(f0 + brow) * KFC + k0 + kseg;

  for (int kc = 0; kc < 4096; kc += 64) {
#pragma unroll
    for (int s = 0; s < 2; ++s) {
      int idx = tid + (s << 8);
      gl_lds16(xrow[s] + kc, &As[idx * 8]);
    }
    float4 w0 = *(const float4*)(wrow + kc);
    float4 w1 = *(const float4*)(wrow + kc + 4);
    float4 w2 = *(const float4*)(wrow + kc + 8);
    float4 w3 = *(const float4*)(wrow + kc + 12);
    *(u16x8*)&Bs[brow * 64 + kseg]     = pack8(w0, w1);
    *(u16x8*)&Bs[brow * 64 + kseg + 8] = pack8(w2, w3);
    __syncthreads();
#pragma unroll
    for (int kk = 0; kk < 2; ++kk) {
      bf16x8 bfv = *(const bf16x8*)&Bs[(wave * 16 + la) * 64 + kk * 32 + lb * 8];
#pragma unroll
      for (int mi = 0; mi < 4; ++mi) {
        bf16x8 av = *(const bf16x8*)&As[(mi * 16 + la) * 64 + kk * 32 + lb * 8];
        acc[mi] = mfma16(av, bfv, acc[mi]);
      }
    }
    __syncthreads();
  }

#pragma unroll
  for (int mi = 0; mi < 4; ++mi) {
    int row = mi * 16 + lb * 4;
#pragma unroll
    for (int r = 0; r < 4; ++r)
      atomicAdd(&hacc[(size_t)(row + r) * NF + f0 + wave * 16 + la], acc[mi][r]);
  }
}

// ---------------------------------------------------------------------------
// FC2 + bias/relu on FC1 output. grid 64 (per batch), block 256.
// ---------------------------------------------------------------------------
__global__ __launch_bounds__(256) void fc2_out(
    const float* __restrict__ hacc, const float* __restrict__ bf1,
    const float* __restrict__ Wf2, const float* __restrict__ bf2,
    float* __restrict__ out)
{
  const int b = blockIdx.x, tid = threadIdx.x;
  float a[8];
#pragma unroll
  for (int o = 0; o < 8; ++o) a[o] = 0.f;
  for (int f = tid; f < NF; f += 256) {
    float hv = fmaxf(hacc[(size_t)b * NF + f] + bf1[f], 0.f);
#pragma unroll
    for (int o = 0; o < 8; ++o) a[o] += hv * Wf2[o * NF + f];
  }
  __shared__ float red[8][256];
#pragma unroll
  for (int o = 0; o < 8; ++o) red[o][tid] = a[o];
  __syncthreads();
  for (int s = 128; s > 0; s >>= 1) {
    if (tid < s) {
#pragma unroll
      for (int o = 0; o < 8; ++o) red[o][tid] += red[o][tid + s];
    }
    __syncthreads();
  }
  if (tid < 8) out[b * 8 + tid] = red[tid][0] + bf2[tid];
}

// ---------------------------------------------------------------------------
extern "C" void kernel_launch(void* const* d_in, const int* in_sizes, int n_in,
                              void* d_out, int out_size, void* d_ws, size_t ws_size,
                              hipStream_t stream) {
  const float* f1  = (const float*)d_in[0];
  const float* f2  = (const float*)d_in[1];
  const float* W1  = (const float*)d_in[2];
  const float* b1  = (const float*)d_in[3];
  const float* g1  = (const float*)d_in[4];
  const float* be1 = (const float*)d_in[5];
  const float* W2  = (const float*)d_in[6];
  const float* b2  = (const float*)d_in[7];
  const float* g2  = (const float*)d_in[8];
  const float* be2 = (const float*)d_in[9];
  const float* W3  = (const float*)d_in[10];
  const float* b3  = (const float*)d_in[11];
  const float* g3  = (const float*)d_in[12];
  const float* be3 = (const float*)d_in[13];
  const float* Wf1 = (const float*)d_in[14];
  const float* bf1 = (const float*)d_in[15];
  const float* Wf2 = (const float*)d_in[16];
  const float* bf2 = (const float*)d_in[17];
  float* out = (float*)d_out;

  char* ws = (char*)d_ws;
  size_t off = 0;
  auto alloc = [&](size_t bytes) -> void* {
    void* p = ws + off;
    off += (bytes + 255) & ~(size_t)255;
    return p;
  };

  ushort_t* zerot = (ushort_t*)alloc(256);
  float* st1  = (float*)alloc(1024 * 4);
  float* st2  = (float*)alloc(1024 * 4);
  float* st3  = (float*)alloc(1024 * 4);
  float* hacc = (float*)alloc((size_t)NB * NF * 4);
  const size_t zero_bytes = off;

  const size_t SZ_AT   = (size_t)NB * NP * NC * 2;
  const size_t SZ_COST = (size_t)NB * NP * KP1 * 2;
  const size_t SZ_WP1  = (size_t)9 * NOUT * KP1 * 2;
  const size_t SZ_WP23 = (size_t)9 * NOUT * 512 * 2;
  ushort_t* AT    = (ushort_t*)alloc(SZ_AT);
  ushort_t* N2T   = (ushort_t*)alloc(SZ_AT);
  ushort_t* costT = (ushort_t*)alloc(SZ_COST);
  ushort_t* Wp1   = (ushort_t*)alloc(SZ_WP1);
  ushort_t* Wp2   = (ushort_t*)alloc(SZ_WP23);
  ushort_t* Wp3   = (ushort_t*)alloc(SZ_WP23);
  float*    Ybuf  = (float*)alloc((size_t)NROWS * NOUT * 4);
  ushort_t* Xbuf  = (ushort_t*)alloc((size_t)NROWS * NOUT * 2);
  ushort_t* Xf    = (ushort_t*)alloc((size_t)NB * KFC * 2);

  hipMemsetAsync(ws, 0, zero_bytes, stream);
  hipMemsetAsync(costT, 0, SZ_COST, stream);

  l2norm_t<<<dim3(64, 2), 256, 0, stream>>>(f1, f2, AT, N2T);

  pack_w<<<(9 * NOUT * KP1 + 255) / 256, 256, 0, stream>>>(W1, Wp1, 1089, KP1, 9 * NOUT * KP1);
  pack_w<<<(9 * NOUT * 512 + 255) / 256, 256, 0, stream>>>(W2, Wp2, 512, 512, 9 * NOUT * 512);
  pack_w<<<(9 * NOUT * 512 + 255) / 256, 256, 0, stream>>>(W3, Wp3, 512, 512, 9 * NOUT * 512);

  cv_gemm<<<dim3(18, 2, 64), 256, 0, stream>>>(AT, N2T, costT, zerot);

  conv_gemm<<<dim3(512), 256, 0, stream>>>(costT, Wp1, b1, Ybuf, st1, KP1, zerot);
  bn_apply<<<8192, 256, 0, stream>>>(Ybuf, st1, g1, be1, Xbuf);

  conv_gemm<<<dim3(512), 256, 0, stream>>>(Xbuf, Wp2, b2, Ybuf, st2, 512, zerot);
  bn_apply<<<8192, 256, 0, stream>>>(Ybuf, st2, g2, be2, Xbuf);

  conv_gemm<<<dim3(512), 256, 0, stream>>>(Xbuf, Wp3, b3, Ybuf, st3, 512, zerot);
  bn_apply_t<<<dim3(8, 4, 64), 256, 0, stream>>>(Ybuf, st3, g3, be3, Xf);

  fc1_gemm<<<dim3(16, 32), 256, 0, stream>>>(Xf, Wf1, hacc);
  fc2_out<<<64, 256, 0, stream>>>(hacc, bf1, Wf2, bf2, out);

  (void)in_sizes; (void)n_in; (void)out_size; (void)ws_size;
}

// Round 3
// 672.671 us; speedup vs baseline: 1.1952x; 1.1180x over previous
//
#include <hip/hip_runtime.h>
#include <hip/hip_bf16.h>
#include <stdint.h>

// ---------------------------------------------------------------------------
// RegressionNet: cost-volume + 3x conv-BN-relu + 2x FC, bf16 MFMA pipeline.
// R2: convs ported to 4-phase/K-tile counted-vmcnt schedule (T3+T4) with
//     tri-buffered LDS, XOR chunk swizzle via pre-swizzled global source (T2),
//     setprio around MFMA clusters (T5). BN stats via shuffle+atomics.
// ---------------------------------------------------------------------------

typedef unsigned short ushort_t;
typedef __attribute__((ext_vector_type(8))) short     bf16x8;
typedef __attribute__((ext_vector_type(8))) unsigned short u16x8;
typedef __attribute__((ext_vector_type(4))) unsigned short u16x4;
typedef __attribute__((ext_vector_type(4))) float     f32x4;

#define NB   64
#define NC   256
#define NP   256
#define KCV  256
#define KP1  1152
#define NOUT 512
#define NROWS 16384
#define KFC  131072
#define NF   1024

__device__ __forceinline__ unsigned short f2bf(float x) {
  union { float f; unsigned u; } c; c.f = x;
  unsigned r = c.u + 0x7FFFu + ((c.u >> 16) & 1u);
  return (unsigned short)(r >> 16);
}

__device__ __forceinline__ void gl_lds16(const void* g, void* l) {
  __builtin_amdgcn_global_load_lds(
      (const __attribute__((address_space(1))) unsigned int*)g,
      (__attribute__((address_space(3))) unsigned int*)l, 16, 0, 0);
}

__device__ __forceinline__ f32x4 mfma16(bf16x8 a, bf16x8 b, f32x4 c) {
  return __builtin_amdgcn_mfma_f32_16x16x32_bf16(a, b, c, 0, 0, 0);
}

// ---------------------------------------------------------------------------
// l2-normalize over channels; write pos-major bf16 [b][pos][c].
// ---------------------------------------------------------------------------
__global__ __launch_bounds__(256) void l2norm_t(
    const float* __restrict__ f1, const float* __restrict__ f2,
    ushort_t* __restrict__ AT, ushort_t* __restrict__ N2T)
{
  const float* src = blockIdx.y ? f2 : f1;
  ushort_t*    dst = blockIdx.y ? N2T : AT;
  const int b = blockIdx.x, t = threadIdx.x;
  const float* sb = src + (size_t)b * NC * NP;
  float sq = 0.f;
  for (int c = 0; c < NC; ++c) { float v = sb[c * NP + t]; sq += v * v; }
  float sc = 1.f / fmaxf(sqrtf(sq), 1e-12f);
  ushort_t* db = dst + ((size_t)b * NP + t) * NC;
  for (int c0 = 0; c0 < NC; c0 += 8) {
    u16x8 pk;
#pragma unroll
    for (int q = 0; q < 8; ++q) pk[q] = f2bf(sb[(c0 + q) * NP + t] * sc);
    *(u16x8*)(db + c0) = pk;
  }
}

// ---------------------------------------------------------------------------
// Pack conv weights (OUT, Cin, 3, 3) fp32 -> [tap][out][cin(pad Kp)] bf16.
// ---------------------------------------------------------------------------
__global__ __launch_bounds__(256) void pack_w(
    const float* __restrict__ W, ushort_t* __restrict__ Wp,
    int Cin, int Kp, int total)
{
  int p = blockIdx.x * 256 + threadIdx.x;
  if (p >= total) return;
  int tap = p / (NOUT * Kp);
  int rem = p - tap * (NOUT * Kp);
  int o   = rem / Kp;
  int cin = rem - o * Kp;
  float v = (cin < Cin) ? W[((size_t)o * Cin + cin) * 9 + tap] : 0.f;
  Wp[p] = f2bf(v);
}

// ---------------------------------------------------------------------------
// Cost volume: per-b GEMM (pos x uv over channels), band-gather epilogue.
// grid (18, 2, 64), block 256; tile 128x128, BK=64 (m97 structure).
// ---------------------------------------------------------------------------
__global__ __launch_bounds__(256) void cv_gemm(
    const ushort_t* __restrict__ AT,
    const ushort_t* __restrict__ N2T,
    ushort_t* __restrict__ costT,
    const ushort_t* __restrict__ zerot)
{
  __shared__ ushort_t As[128 * 64];
  __shared__ ushort_t Bs[128 * 64];
  const int tid = threadIdx.x, lane = tid & 63, wave = tid >> 6;
  const int wr = wave >> 1, wc = wave & 1;
  const int la = lane & 15, lb = lane >> 4;
  const int b  = blockIdx.z;
  const int m0 = blockIdx.y * 128;
  const int n0 = blockIdx.x * 128;

  f32x4 acc[4][4];
#pragma unroll
  for (int i = 0; i < 4; ++i)
#pragma unroll
    for (int j = 0; j < 4; ++j) acc[i][j] = (f32x4){0.f, 0.f, 0.f, 0.f};

  const ushort_t* srcA[4];
  const ushort_t* srcB[4];
#pragma unroll
  for (int s = 0; s < 4; ++s) {
    int idx = tid + (s << 8);
    int row = idx >> 3, c16 = idx & 7;
    srcA[s] = AT + ((size_t)b * NP + m0 + row) * NC + c16 * 8;
    int uv = n0 + row;
    int u = uv / 48, v = uv - u * 48;
    int oi = u - 16, oj = v - 16;
    bool val = ((unsigned)oi < 16u) & ((unsigned)oj < 16u);
    srcB[s] = val ? (N2T + ((size_t)b * NP + oi * 16 + oj) * NC + c16 * 8)
                  : (const ushort_t*)0;
  }

  for (int kc = 0; kc < KCV; kc += 64) {
#pragma unroll
    for (int s = 0; s < 4; ++s) {
      int idx = tid + (s << 8);
      gl_lds16(srcA[s] + kc, &As[idx * 8]);
      const ushort_t* g = srcB[s] ? srcB[s] + kc : zerot;
      gl_lds16(g, &Bs[idx * 8]);
    }
    __syncthreads();
#pragma unroll
    for (int kk = 0; kk < 2; ++kk) {
      bf16x8 af[4], bfv[4];
#pragma unroll
      for (int mi = 0; mi < 4; ++mi)
        af[mi] = *(const bf16x8*)&As[(wr * 64 + mi * 16 + la) * 64 + kk * 32 + lb * 8];
#pragma unroll
      for (int ni = 0; ni < 4; ++ni)
        bfv[ni] = *(const bf16x8*)&Bs[(wc * 64 + ni * 16 + la) * 64 + kk * 32 + lb * 8];
#pragma unroll
      for (int mi = 0; mi < 4; ++mi)
#pragma unroll
        for (int ni = 0; ni < 4; ++ni)
          acc[mi][ni] = mfma16(af[mi], bfv[ni], acc[mi][ni]);
    }
    __syncthreads();
  }

  const float sc = 1.f / 256.f;
#pragma unroll
  for (int ni = 0; ni < 4; ++ni) {
    int uv = n0 + wc * 64 + ni * 16 + la;
    int u = uv / 48, v = uv - u * 48;
#pragma unroll
    for (int mi = 0; mi < 4; ++mi) {
      int ij = m0 + wr * 64 + mi * 16 + lb * 4;
#pragma unroll
      for (int r = 0; r < 4; ++r) {
        int ijr = ij + r;
        int i = ijr >> 4, j = ijr & 15;
        int dy = u - i, dx = v - j;
        if ((unsigned)dy < 33u && (unsigned)dx < 33u) {
          float vv = acc[mi][ni][r] * sc;
          vv = vv > 0.f ? vv : 0.01f * vv;
          costT[((size_t)b * NP + ijr) * KP1 + dy * 33 + dx] = f2bf(vv);
        }
      }
    }
  }
}

// ---------------------------------------------------------------------------
// Conv 3x3 as tap-decomposed GEMM, 4-phase/K-tile counted-vmcnt schedule.
// X: [16384][K] bf16, Wp: [9][512][K] bf16, Y: [16384][512] fp32 (+bias).
// BM=256 (one image), BN=128, BK=64; block 512 (8 waves, 4Mx2N); grid 256.
// Tri-buffer LDS (3 x 48KB); stage tile t+2 while computing tile t; vmcnt(6)
// at group boundaries (6 gl_lds/thread/tile). Chunk-XOR swizzle on global
// source + reads (LDS linear) kills the 16-way ds_read bank conflict.
// BN stats fused: shuffle-reduce over lb + per-col atomicAdd.
// ---------------------------------------------------------------------------
__global__ __launch_bounds__(512, 2) void conv_gemm8(
    const ushort_t* __restrict__ X, const ushort_t* __restrict__ Wp,
    const float* __restrict__ bias, float* __restrict__ Y,
    float* __restrict__ st, const int K, const int TPT, const int NT,
    const ushort_t* __restrict__ zerot)
{
  __shared__ ushort_t lds[3 * 24576];   // per buf: A[256*64] then B[128*64]
  const int tid = threadIdx.x;
  const int lane = tid & 63, wave = tid >> 6;
  const int wr = wave >> 1, wc = wave & 1;
  const int la = lane & 15, lb = lane >> 4;

  const int wg = blockIdx.x;
  const int sw = ((wg & 7) << 5) + (wg >> 3);   // XCD swizzle, bijective (256%8==0)
  const int b  = sw >> 2;                       // m-tile == batch
  const int n0 = (sw & 3) * 128;

  // --- per-thread staging precompute ---
  int amask[4];
  const ushort_t* abase[4];
#pragma unroll
  for (int s = 0; s < 4; ++s) {
    int idx = tid + (s << 9);
    int row = idx >> 3, cs = idx & 7;
    int i = row >> 4, j = row & 15;
    int m = 0;
#pragma unroll
    for (int tap = 0; tap < 9; ++tap) {
      int i2 = i + tap / 3 - 1, j2 = j + tap % 3 - 1;
      if (((unsigned)i2 < 16u) & ((unsigned)j2 < 16u)) m |= 1 << tap;
    }
    amask[s] = m;
    abase[s] = X + (size_t)(b * NP + row) * K + ((cs ^ (row & 7)) << 3);
  }
  const ushort_t* bbase[2];
#pragma unroll
  for (int s = 0; s < 2; ++s) {
    int idx = tid + (s << 9);
    int row = idx >> 3, cs = idx & 7;
    bbase[s] = Wp + (size_t)(n0 + row) * K + ((cs ^ (row & 7)) << 3);
  }

  // frag read offsets (elements, within buf)
  const int sw0 = ((0 + lb) ^ (la & 7)) << 3;
  const int sw1 = ((4 + lb) ^ (la & 7)) << 3;
  const int arow = (wr * 64 + la) * 64;
  const int brow = 16384 + (wc * 64 + la) * 64;

  f32x4 acc[4][4];
#pragma unroll
  for (int i = 0; i < 4; ++i)
#pragma unroll
    for (int j = 0; j < 4; ++j) acc[i][j] = (f32x4){0.f, 0.f, 0.f, 0.f};

  // tile-parameter helper (uniform): tap, kc offset, weight tap base
  auto tile_par = [&](int t, int& toffA, size_t& wtap, int& tap, int& kc) {
    tap = t / TPT;
    kc  = (t - tap * TPT) << 6;
    int ty = tap / 3;
    toffA = (ty * 16 + (tap - 3 * ty) - 17) * K + kc;   // ((ty-1)*16 + tx-1)*K + kc
    wtap  = (size_t)tap * NOUT * K + kc;
  };

  // prologue: stage tiles 0 and 1 (tap 0 for both; TPT >= 8)
  {
    int toffA, tap, kc; size_t wtap;
#pragma unroll
    for (int t = 0; t < 2; ++t) {
      tile_par(t, toffA, wtap, tap, kc);
      ushort_t* buf = &lds[t * 24576];
#pragma unroll
      for (int s = 0; s < 4; ++s) {
        const ushort_t* g = ((amask[s] >> tap) & 1) ? abase[s] + toffA : zerot;
        gl_lds16(g, &buf[(tid + (s << 9)) * 8]);
      }
#pragma unroll
      for (int s = 0; s < 2; ++s)
        gl_lds16(bbase[s] + wtap, &buf[16384 + (tid + (s << 9)) * 8]);
    }
  }
  asm volatile("s_waitcnt vmcnt(6)" ::: "memory");
  __builtin_amdgcn_s_barrier();

  for (int t = 0; t < NT; ++t) {
    const int q = t % 3;
    const ushort_t* buf = &lds[q * 24576];
    const int t2 = t + 2;
    const bool do_stage = t2 < NT;
    int toffA2 = 0, tap2 = 0, kc2 = 0; size_t wtap2 = 0;
    ushort_t* buf2 = &lds[0];
    if (do_stage) {
      tile_par(t2, toffA2, wtap2, tap2, kc2);
      buf2 = &lds[(t2 % 3) * 24576];
    }

    bf16x8 Af[4][2], Bf[4][2];
    // ---------------- P0: A(mi0-1), B(ni0-1) reads; stage A slots 0-1 -----
    Af[0][0] = *(const bf16x8*)&buf[arow + 0 * 1024 + sw0];
    Af[0][1] = *(const bf16x8*)&buf[arow + 0 * 1024 + sw1];
    Af[1][0] = *(const bf16x8*)&buf[arow + 1 * 1024 + sw0];
    Af[1][1] = *(const bf16x8*)&buf[arow + 1 * 1024 + sw1];
    Bf[0][0] = *(const bf16x8*)&buf[brow + 0 * 1024 + sw0];
    Bf[0][1] = *(const bf16x8*)&buf[brow + 0 * 1024 + sw1];
    Bf[1][0] = *(const bf16x8*)&buf[brow + 1 * 1024 + sw0];
    Bf[1][1] = *(const bf16x8*)&buf[brow + 1 * 1024 + sw1];
    if (do_stage) {
#pragma unroll
      for (int s = 0; s < 2; ++s) {
        const ushort_t* g = ((amask[s] >> tap2) & 1) ? abase[s] + toffA2 : zerot;
        gl_lds16(g, &buf2[(tid + (s << 9)) * 8]);
      }
    }
    __builtin_amdgcn_s_barrier();
    asm volatile("s_waitcnt lgkmcnt(0)" ::: "memory");
    __builtin_amdgcn_sched_barrier(0);
    __builtin_amdgcn_s_setprio(1);
    acc[0][0] = mfma16(Af[0][0], Bf[0][0], acc[0][0]);
    acc[0][0] = mfma16(Af[0][1], Bf[0][1], acc[0][0]);
    acc[0][1] = mfma16(Af[0][0], Bf[1][0], acc[0][1]);
    acc[0][1] = mfma16(Af[0][1], Bf[1][1], acc[0][1]);
    acc[1][0] = mfma16(Af[1][0], Bf[0][0], acc[1][0]);
    acc[1][0] = mfma16(Af[1][1], Bf[0][1], acc[1][0]);
    acc[1][1] = mfma16(Af[1][0], Bf[1][0], acc[1][1]);
    acc[1][1] = mfma16(Af[1][1], Bf[1][1], acc[1][1]);
    __builtin_amdgcn_s_setprio(0);
    __builtin_amdgcn_s_barrier();
    // ---------------- P1: A(mi2-3) reads; stage A slots 2-3 ---------------
    Af[2][0] = *(const bf16x8*)&buf[arow + 2 * 1024 + sw0];
    Af[2][1] = *(const bf16x8*)&buf[arow + 2 * 1024 + sw1];
    Af[3][0] = *(const bf16x8*)&buf[arow + 3 * 1024 + sw0];
    Af[3][1] = *(const bf16x8*)&buf[arow + 3 * 1024 + sw1];
    if (do_stage) {
#pragma unroll
      for (int s = 2; s < 4; ++s) {
        const ushort_t* g = ((amask[s] >> tap2) & 1) ? abase[s] + toffA2 : zerot;
        gl_lds16(g, &buf2[(tid + (s << 9)) * 8]);
      }
    }
    __builtin_amdgcn_s_barrier();
    asm volatile("s_waitcnt lgkmcnt(0)" ::: "memory");
    __builtin_amdgcn_sched_barrier(0);
    __builtin_amdgcn_s_setprio(1);
    acc[2][0] = mfma16(Af[2][0], Bf[0][0], acc[2][0]);
    acc[2][0] = mfma16(Af[2][1], Bf[0][1], acc[2][0]);
    acc[2][1] = mfma16(Af[2][0], Bf[1][0], acc[2][1]);
    acc[2][1] = mfma16(Af[2][1], Bf[1][1], acc[2][1]);
    acc[3][0] = mfma16(Af[3][0], Bf[0][0], acc[3][0]);
    acc[3][0] = mfma16(Af[3][1], Bf[0][1], acc[3][0]);
    acc[3][1] = mfma16(Af[3][0], Bf[1][0], acc[3][1]);
    acc[3][1] = mfma16(Af[3][1], Bf[1][1], acc[3][1]);
    __builtin_amdgcn_s_setprio(0);
    __builtin_amdgcn_s_barrier();
    // ---------------- P2: B(ni2-3) reads; stage B slots 0-1 ---------------
    Bf[2][0] = *(const bf16x8*)&buf[brow + 2 * 1024 + sw0];
    Bf[2][1] = *(const bf16x8*)&buf[brow + 2 * 1024 + sw1];
    Bf[3][0] = *(const bf16x8*)&buf[brow + 3 * 1024 + sw0];
    Bf[3][1] = *(const bf16x8*)&buf[brow + 3 * 1024 + sw1];
    if (do_stage) {
#pragma unroll
      for (int s = 0; s < 2; ++s)
        gl_lds16(bbase[s] + wtap2, &buf2[16384 + (tid + (s << 9)) * 8]);
    }
    __builtin_amdgcn_s_barrier();
    asm volatile("s_waitcnt lgkmcnt(0)" ::: "memory");
    __builtin_amdgcn_sched_barrier(0);
    __builtin_amdgcn_s_setprio(1);
    acc[0][2] = mfma16(Af[0][0], Bf[2][0], acc[0][2]);
    acc[0][2] = mfma16(Af[0][1], Bf[2][1], acc[0][2]);
    acc[0][3] = mfma16(Af[0][0], Bf[3][0], acc[0][3]);
    acc[0][3] = mfma16(Af[0][1], Bf[3][1], acc[0][3]);
    acc[1][2] = mfma16(Af[1][0], Bf[2][0], acc[1][2]);
    acc[1][2] = mfma16(Af[1][1], Bf[2][1], acc[1][2]);
    acc[1][3] = mfma16(Af[1][0], Bf[3][0], acc[1][3]);
    acc[1][3] = mfma16(Af[1][1], Bf[3][1], acc[1][3]);
    __builtin_amdgcn_s_setprio(0);
    __builtin_amdgcn_s_barrier();
    // ---------------- P3: remaining quadrant; counted vmcnt ---------------
    __builtin_amdgcn_s_setprio(1);
    acc[2][2] = mfma16(Af[2][0], Bf[2][0], acc[2][2]);
    acc[2][2] = mfma16(Af[2][1], Bf[2][1], acc[2][2]);
    acc[2][3] = mfma16(Af[2][0], Bf[3][0], acc[2][3]);
    acc[2][3] = mfma16(Af[2][1], Bf[3][1], acc[2][3]);
    acc[3][2] = mfma16(Af[3][0], Bf[2][0], acc[3][2]);
    acc[3][2] = mfma16(Af[3][1], Bf[2][1], acc[3][2]);
    acc[3][3] = mfma16(Af[3][0], Bf[3][0], acc[3][3]);
    acc[3][3] = mfma16(Af[3][1], Bf[3][1], acc[3][3]);
    __builtin_amdgcn_s_setprio(0);
    if (do_stage) asm volatile("s_waitcnt vmcnt(6)" ::: "memory");
    else          asm volatile("s_waitcnt vmcnt(0)" ::: "memory");
    __builtin_amdgcn_s_barrier();
  }

  // epilogue: bias + Y write + fused BN stats (shuffle over lb, atomics)
#pragma unroll
  for (int ni = 0; ni < 4; ++ni) {
    int col = n0 + wc * 64 + ni * 16 + la;
    float bv = bias[col];
    float s = 0.f, qq = 0.f;
#pragma unroll
    for (int mi = 0; mi < 4; ++mi) {
      int row = b * NP + wr * 64 + mi * 16 + lb * 4;
#pragma unroll
      for (int r = 0; r < 4; ++r) {
        float v = acc[mi][ni][r] + bv;
        Y[(size_t)(row + r) * NOUT + col] = v;
        s += v; qq += v * v;
      }
    }
    s  += __shfl_xor(s, 16);  s  += __shfl_xor(s, 32);
    qq += __shfl_xor(qq, 16); qq += __shfl_xor(qq, 32);
    if (lb == 0) {
      atomicAdd(&st[col], s);
      atomicAdd(&st[512 + col], qq);
    }
  }
}

// ---------------------------------------------------------------------------
// BN apply + relu + bf16 cast, same-layout output [m][c].
// ---------------------------------------------------------------------------
__global__ __launch_bounds__(256) void bn_apply(
    const float* __restrict__ Y, const float* __restrict__ st,
    const float* __restrict__ g, const float* __restrict__ be,
    ushort_t* __restrict__ Xo)
{
  const int idx = blockIdx.x * 256 + threadIdx.x;
  const float4 y = *(const float4*)(Y + (size_t)idx * 4);
  const int c0 = (idx * 4) & 511;
  const float yv[4] = {y.x, y.y, y.z, y.w};
  u16x4 pk;
#pragma unroll
  for (int q = 0; q < 4; ++q) {
    int c = c0 + q;
    float mu  = st[c] * (1.f / 16384.f);
    float var = st[512 + c] * (1.f / 16384.f) - mu * mu;
    float s = rsqrtf(var + 1e-5f) * g[c];
    pk[q] = f2bf(fmaxf((yv[q] - mu) * s + be[c], 0.f));
  }
  *(u16x4*)(Xo + (size_t)idx * 4) = pk;
}

// ---------------------------------------------------------------------------
// BN apply + relu + bf16, transposed to FC layout Xf[b][c*256+ij].
// ---------------------------------------------------------------------------
__global__ __launch_bounds__(256) void bn_apply_t(
    const float* __restrict__ Y, const float* __restrict__ st,
    const float* __restrict__ g, const float* __restrict__ be,
    ushort_t* __restrict__ Xf)
{
  __shared__ ushort_t T[64][65];
  const int c0  = blockIdx.x * 64;
  const int ij0 = blockIdx.y * 64;
  const int b   = blockIdx.z;
  const int tid = threadIdx.x;

#pragma unroll
  for (int it = 0; it < 16; ++it) {
    int e = it * 256 + tid;
    int ij = e >> 6, c = e & 63;
    int cg = c0 + c;
    float y = Y[((size_t)(b * NP + ij0 + ij)) * NOUT + cg];
    float mu  = st[cg] * (1.f / 16384.f);
    float var = st[512 + cg] * (1.f / 16384.f) - mu * mu;
    float s = rsqrtf(var + 1e-5f) * g[cg];
    T[ij][c] = f2bf(fmaxf((y - mu) * s + be[cg], 0.f));
  }
  __syncthreads();
#pragma unroll
  for (int it = 0; it < 16; ++it) {
    int e = it * 256 + tid;
    int cr = e >> 6, ijc = e & 63;
    Xf[(size_t)b * KFC + (size_t)(c0 + cr) * NP + ij0 + ijc] = T[ijc][cr];
  }
}

// ---------------------------------------------------------------------------
// FC1: (64 x 131072) bf16 @ (1024 x 131072)^T fp32->bf16, split-K atomics.
// ---------------------------------------------------------------------------
__device__ __forceinline__ u16x8 pack8(float4 a, float4 b) {
  u16x8 r;
  r[0] = f2bf(a.x); r[1] = f2bf(a.y); r[2] = f2bf(a.z); r[3] = f2bf(a.w);
  r[4] = f2bf(b.x); r[5] = f2bf(b.y); r[6] = f2bf(b.z); r[7] = f2bf(b.w);
  return r;
}

__global__ __launch_bounds__(256) void fc1_gemm(
    const ushort_t* __restrict__ Xf, const float* __restrict__ Wf1,
    float* __restrict__ hacc)
{
  __shared__ ushort_t As[64 * 64];
  __shared__ ushort_t Bs[64 * 64];
  const int tid = threadIdx.x, lane = tid & 63, wave = tid >> 6;
  const int la = lane & 15, lb = lane >> 4;
  const int f0 = blockIdx.x * 64;
  const int k0 = blockIdx.y * 4096;

  f32x4 acc[4];
#pragma unroll
  for (int i = 0; i < 4; ++i) acc[i] = (f32x4){0.f, 0.f, 0.f, 0.f};

  const ushort_t* xrow[2];
#pragma unroll
  for (int s = 0; s < 2; ++s) {
    int idx = tid + (s << 8);
    xrow[s] = Xf + (size_t)(idx >> 3) * KFC + k0 + (idx & 7) * 8;
  }
  const int brow = tid >> 2, kseg = (tid & 3) * 16;
  const float* wrow = Wf1 + (size_t)(f0 + brow) * KFC + k0 + kseg;

  for (int kc = 0; kc < 4096; kc += 64) {
#pragma unroll
    for (int s = 0; s < 2; ++s) {
      int idx = tid + (s << 8);
      gl_lds16(xrow[s] + kc, &As[idx * 8]);
    }
    float4 w0 = *(const float4*)(wrow + kc);
    float4 w1 = *(const float4*)(wrow + kc + 4);
    float4 w2 = *(const float4*)(wrow + kc + 8);
    float4 w3 = *(const float4*)(wrow + kc + 12);
    *(u16x8*)&Bs[brow * 64 + kseg]     = pack8(w0, w1);
    *(u16x8*)&Bs[brow * 64 + kseg + 8] = pack8(w2, w3);
    __syncthreads();
#pragma unroll
    for (int kk = 0; kk < 2; ++kk) {
      bf16x8 bfv = *(const bf16x8*)&Bs[(wave * 16 + la) * 64 + kk * 32 + lb * 8];
#pragma unroll
      for (int mi = 0; mi < 4; ++mi) {
        bf16x8 av = *(const bf16x8*)&As[(mi * 16 + la) * 64 + kk * 32 + lb * 8];
        acc[mi] = mfma16(av, bfv, acc[mi]);
      }
    }
    __syncthreads();
  }

#pragma unroll
  for (int mi = 0; mi < 4; ++mi) {
    int row = mi * 16 + lb * 4;
#pragma unroll
    for (int r = 0; r < 4; ++r)
      atomicAdd(&hacc[(size_t)(row + r) * NF + f0 + wave * 16 + la], acc[mi][r]);
  }
}

// ---------------------------------------------------------------------------
// FC2 + bias/relu on FC1 output. grid 64, block 256.
// ---------------------------------------------------------------------------
__global__ __launch_bounds__(256) void fc2_out(
    const float* __restrict__ hacc, const float* __restrict__ bf1,
    const float* __restrict__ Wf2, const float* __restrict__ bf2,
    float* __restrict__ out)
{
  const int b = blockIdx.x, tid = threadIdx.x;
  float a[8];
#pragma unroll
  for (int o = 0; o < 8; ++o) a[o] = 0.f;
  for (int f = tid; f < NF; f += 256) {
    float hv = fmaxf(hacc[(size_t)b * NF + f] + bf1[f], 0.f);
#pragma unroll
    for (int o = 0; o < 8; ++o) a[o] += hv * Wf2[o * NF + f];
  }
  __shared__ float red[8][256];
#pragma unroll
  for (int o = 0; o < 8; ++o) red[o][tid] = a[o];
  __syncthreads();
  for (int s = 128; s > 0; s >>= 1) {
    if (tid < s) {
#pragma unroll
      for (int o = 0; o < 8; ++o) red[o][tid] += red[o][tid + s];
    }
    __syncthreads();
  }
  if (tid < 8) out[b * 8 + tid] = red[tid][0] + bf2[tid];
}

// ---------------------------------------------------------------------------
extern "C" void kernel_launch(void* const* d_in, const int* in_sizes, int n_in,
                              void* d_out, int out_size, void* d_ws, size_t ws_size,
                              hipStream_t stream) {
  const float* f1  = (const float*)d_in[0];
  const float* f2  = (const float*)d_in[1];
  const float* W1  = (const float*)d_in[2];
  const float* b1  = (const float*)d_in[3];
  const float* g1  = (const float*)d_in[4];
  const float* be1 = (const float*)d_in[5];
  const float* W2  = (const float*)d_in[6];
  const float* b2  = (const float*)d_in[7];
  const float* g2  = (const float*)d_in[8];
  const float* be2 = (const float*)d_in[9];
  const float* W3  = (const float*)d_in[10];
  const float* b3  = (const float*)d_in[11];
  const float* g3  = (const float*)d_in[12];
  const float* be3 = (const float*)d_in[13];
  const float* Wf1 = (const float*)d_in[14];
  const float* bf1 = (const float*)d_in[15];
  const float* Wf2 = (const float*)d_in[16];
  const float* bf2 = (const float*)d_in[17];
  float* out = (float*)d_out;

  char* ws = (char*)d_ws;
  size_t off = 0;
  auto alloc = [&](size_t bytes) -> void* {
    void* p = ws + off;
    off += (bytes + 255) & ~(size_t)255;
    return p;
  };

  ushort_t* zerot = (ushort_t*)alloc(256);
  float* st1  = (float*)alloc(1024 * 4);
  float* st2  = (float*)alloc(1024 * 4);
  float* st3  = (float*)alloc(1024 * 4);
  float* hacc = (float*)alloc((size_t)NB * NF * 4);
  const size_t zero_bytes = off;

  const size_t SZ_AT   = (size_t)NB * NP * NC * 2;
  const size_t SZ_COST = (size_t)NB * NP * KP1 * 2;
  const size_t SZ_WP1  = (size_t)9 * NOUT * KP1 * 2;
  const size_t SZ_WP23 = (size_t)9 * NOUT * 512 * 2;
  ushort_t* AT    = (ushort_t*)alloc(SZ_AT);
  ushort_t* N2T   = (ushort_t*)alloc(SZ_AT);
  ushort_t* costT = (ushort_t*)alloc(SZ_COST);
  ushort_t* Wp1   = (ushort_t*)alloc(SZ_WP1);
  ushort_t* Wp2   = (ushort_t*)alloc(SZ_WP23);
  ushort_t* Wp3   = (ushort_t*)alloc(SZ_WP23);
  float*    Ybuf  = (float*)alloc((size_t)NROWS * NOUT * 4);
  ushort_t* Xbuf  = (ushort_t*)alloc((size_t)NROWS * NOUT * 2);
  ushort_t* Xf    = (ushort_t*)alloc((size_t)NB * KFC * 2);

  hipMemsetAsync(ws, 0, zero_bytes, stream);
  hipMemsetAsync(costT, 0, SZ_COST, stream);

  l2norm_t<<<dim3(64, 2), 256, 0, stream>>>(f1, f2, AT, N2T);

  pack_w<<<(9 * NOUT * KP1 + 255) / 256, 256, 0, stream>>>(W1, Wp1, 1089, KP1, 9 * NOUT * KP1);
  pack_w<<<(9 * NOUT * 512 + 255) / 256, 256, 0, stream>>>(W2, Wp2, 512, 512, 9 * NOUT * 512);
  pack_w<<<(9 * NOUT * 512 + 255) / 256, 256, 0, stream>>>(W3, Wp3, 512, 512, 9 * NOUT * 512);

  cv_gemm<<<dim3(18, 2, 64), 256, 0, stream>>>(AT, N2T, costT, zerot);

  conv_gemm8<<<256, 512, 0, stream>>>(costT, Wp1, b1, Ybuf, st1, KP1, 18, 162, zerot);
  bn_apply<<<8192, 256, 0, stream>>>(Ybuf, st1, g1, be1, Xbuf);

  conv_gemm8<<<256, 512, 0, stream>>>(Xbuf, Wp2, b2, Ybuf, st2, 512, 8, 72, zerot);
  bn_apply<<<8192, 256, 0, stream>>>(Ybuf, st2, g2, be2, Xbuf);

  conv_gemm8<<<256, 512, 0, stream>>>(Xbuf, Wp3, b3, Ybuf, st3, 512, 8, 72, zerot);
  bn_apply_t<<<dim3(8, 4, 64), 256, 0, stream>>>(Ybuf, st3, g3, be3, Xf);

  fc1_gemm<<<dim3(16, 32), 256, 0, stream>>>(Xf, Wf1, hacc);
  fc2_out<<<64, 256, 0, stream>>>(hacc, bf1, Wf2, bf2, out);

  (void)in_sizes; (void)n_in; (void)out_size; (void)ws_size;
}

// Round 4
// 630.819 us; speedup vs baseline: 1.2745x; 1.0663x over previous
//
#include <hip/hip_runtime.h>
#include <hip/hip_bf16.h>
#include <stdint.h>

// ---------------------------------------------------------------------------
// RegressionNet: cost-volume + 3x conv-BN-relu + 2x FC, bf16 MFMA pipeline.
// R3: conv phases reordered (kk-outer => MFMA dependency distance 4),
//     one barrier per phase (4/tile instead of 8), cv band-empty block skip,
//     fc1 split-K via slice stores (no atomics) + fc2 slice reduction.
// ---------------------------------------------------------------------------

typedef unsigned short ushort_t;
typedef __attribute__((ext_vector_type(8))) short     bf16x8;
typedef __attribute__((ext_vector_type(8))) unsigned short u16x8;
typedef __attribute__((ext_vector_type(4))) unsigned short u16x4;
typedef __attribute__((ext_vector_type(4))) float     f32x4;

#define NB   64
#define NC   256
#define NP   256
#define KCV  256
#define KP1  1152
#define NOUT 512
#define NROWS 16384
#define KFC  131072
#define NF   1024
#define KSPL 32      // fc1 k-splits

__device__ __forceinline__ unsigned short f2bf(float x) {
  union { float f; unsigned u; } c; c.f = x;
  unsigned r = c.u + 0x7FFFu + ((c.u >> 16) & 1u);
  return (unsigned short)(r >> 16);
}

__device__ __forceinline__ void gl_lds16(const void* g, void* l) {
  __builtin_amdgcn_global_load_lds(
      (const __attribute__((address_space(1))) unsigned int*)g,
      (__attribute__((address_space(3))) unsigned int*)l, 16, 0, 0);
}

__device__ __forceinline__ f32x4 mfma16(bf16x8 a, bf16x8 b, f32x4 c) {
  return __builtin_amdgcn_mfma_f32_16x16x32_bf16(a, b, c, 0, 0, 0);
}

// ---------------------------------------------------------------------------
// l2-normalize over channels; write pos-major bf16 [b][pos][c].
// ---------------------------------------------------------------------------
__global__ __launch_bounds__(256) void l2norm_t(
    const float* __restrict__ f1, const float* __restrict__ f2,
    ushort_t* __restrict__ AT, ushort_t* __restrict__ N2T)
{
  const float* src = blockIdx.y ? f2 : f1;
  ushort_t*    dst = blockIdx.y ? N2T : AT;
  const int b = blockIdx.x, t = threadIdx.x;
  const float* sb = src + (size_t)b * NC * NP;
  float sq = 0.f;
  for (int c = 0; c < NC; ++c) { float v = sb[c * NP + t]; sq += v * v; }
  float sc = 1.f / fmaxf(sqrtf(sq), 1e-12f);
  ushort_t* db = dst + ((size_t)b * NP + t) * NC;
  for (int c0 = 0; c0 < NC; c0 += 8) {
    u16x8 pk;
#pragma unroll
    for (int q = 0; q < 8; ++q) pk[q] = f2bf(sb[(c0 + q) * NP + t] * sc);
    *(u16x8*)(db + c0) = pk;
  }
}

// ---------------------------------------------------------------------------
// Pack conv weights (OUT, Cin, 3, 3) fp32 -> [tap][out][cin(pad Kp)] bf16.
// ---------------------------------------------------------------------------
__global__ __launch_bounds__(256) void pack_w(
    const float* __restrict__ W, ushort_t* __restrict__ Wp,
    int Cin, int Kp, int total)
{
  int p = blockIdx.x * 256 + threadIdx.x;
  if (p >= total) return;
  int tap = p / (NOUT * Kp);
  int rem = p - tap * (NOUT * Kp);
  int o   = rem / Kp;
  int cin = rem - o * Kp;
  float v = (cin < Cin) ? W[((size_t)o * Cin + cin) * 9 + tap] : 0.f;
  Wp[p] = f2bf(v);
}

// ---------------------------------------------------------------------------
// Cost volume: per-b GEMM (pos x uv over channels), band-gather epilogue.
// grid (18, 2, 64), block 256; tile 128x128, BK=64. Band-empty blocks skip.
// ---------------------------------------------------------------------------
__global__ __launch_bounds__(256) void cv_gemm(
    const ushort_t* __restrict__ AT,
    const ushort_t* __restrict__ N2T,
    ushort_t* __restrict__ costT,
    const ushort_t* __restrict__ zerot)
{
  __shared__ ushort_t As[128 * 64];
  __shared__ ushort_t Bs[128 * 64];
  const int tid = threadIdx.x, lane = tid & 63, wave = tid >> 6;
  const int wr = wave >> 1, wc = wave & 1;
  const int la = lane & 15, lb = lane >> 4;
  const int b  = blockIdx.z;
  const int m0 = blockIdx.y * 128;
  const int n0 = blockIdx.x * 128;

  // band-empty skip: this block's uv rows have u outside [i, i+32] entirely
  {
    const int iMin = blockIdx.y * 8, iMax = iMin + 7;
    const int uMin = n0 / 48, uMax = (n0 + 127) / 48;
    if (uMax < iMin || uMin > iMax + 32) return;
  }

  f32x4 acc[4][4];
#pragma unroll
  for (int i = 0; i < 4; ++i)
#pragma unroll
    for (int j = 0; j < 4; ++j) acc[i][j] = (f32x4){0.f, 0.f, 0.f, 0.f};

  const ushort_t* srcA[4];
  const ushort_t* srcB[4];
#pragma unroll
  for (int s = 0; s < 4; ++s) {
    int idx = tid + (s << 8);
    int row = idx >> 3, c16 = idx & 7;
    srcA[s] = AT + ((size_t)b * NP + m0 + row) * NC + c16 * 8;
    int uv = n0 + row;
    int u = uv / 48, v = uv - u * 48;
    int oi = u - 16, oj = v - 16;
    bool val = ((unsigned)oi < 16u) & ((unsigned)oj < 16u);
    srcB[s] = val ? (N2T + ((size_t)b * NP + oi * 16 + oj) * NC + c16 * 8)
                  : (const ushort_t*)0;
  }

  for (int kc = 0; kc < KCV; kc += 64) {
#pragma unroll
    for (int s = 0; s < 4; ++s) {
      int idx = tid + (s << 8);
      gl_lds16(srcA[s] + kc, &As[idx * 8]);
      const ushort_t* g = srcB[s] ? srcB[s] + kc : zerot;
      gl_lds16(g, &Bs[idx * 8]);
    }
    __syncthreads();
#pragma unroll
    for (int kk = 0; kk < 2; ++kk) {
      bf16x8 af[4], bfv[4];
#pragma unroll
      for (int mi = 0; mi < 4; ++mi)
        af[mi] = *(const bf16x8*)&As[(wr * 64 + mi * 16 + la) * 64 + kk * 32 + lb * 8];
#pragma unroll
      for (int ni = 0; ni < 4; ++ni)
        bfv[ni] = *(const bf16x8*)&Bs[(wc * 64 + ni * 16 + la) * 64 + kk * 32 + lb * 8];
#pragma unroll
      for (int mi = 0; mi < 4; ++mi)
#pragma unroll
        for (int ni = 0; ni < 4; ++ni)
          acc[mi][ni] = mfma16(af[mi], bfv[ni], acc[mi][ni]);
    }
    __syncthreads();
  }

  const float sc = 1.f / 256.f;
#pragma unroll
  for (int ni = 0; ni < 4; ++ni) {
    int uv = n0 + wc * 64 + ni * 16 + la;
    int u = uv / 48, v = uv - u * 48;
#pragma unroll
    for (int mi = 0; mi < 4; ++mi) {
      int ij = m0 + wr * 64 + mi * 16 + lb * 4;
#pragma unroll
      for (int r = 0; r < 4; ++r) {
        int ijr = ij + r;
        int i = ijr >> 4, j = ijr & 15;
        int dy = u - i, dx = v - j;
        if ((unsigned)dy < 33u && (unsigned)dx < 33u) {
          float vv = acc[mi][ni][r] * sc;
          vv = vv > 0.f ? vv : 0.01f * vv;
          costT[((size_t)b * NP + ijr) * KP1 + dy * 33 + dx] = f2bf(vv);
        }
      }
    }
  }
}

// ---------------------------------------------------------------------------
// Conv 3x3 as tap-decomposed GEMM, 4-phase/K-tile counted-vmcnt schedule.
// R3: kk-outer MFMA order (dep distance 4), 1 barrier per phase.
// BM=256, BN=128, BK=64; block 512 (8 waves, 4Mx2N); grid 256, tri-buffer.
// ---------------------------------------------------------------------------
__global__ __launch_bounds__(512, 2) void conv_gemm8(
    const ushort_t* __restrict__ X, const ushort_t* __restrict__ Wp,
    const float* __restrict__ bias, float* __restrict__ Y,
    float* __restrict__ st, const int K, const int TPT, const int NT,
    const ushort_t* __restrict__ zerot)
{
  __shared__ ushort_t lds[3 * 24576];   // per buf: A[256*64] then B[128*64]
  const int tid = threadIdx.x;
  const int lane = tid & 63, wave = tid >> 6;
  const int wr = wave >> 1, wc = wave & 1;
  const int la = lane & 15, lb = lane >> 4;

  const int wg = blockIdx.x;
  const int sw = ((wg & 7) << 5) + (wg >> 3);   // XCD swizzle (256%8==0)
  const int b  = sw >> 2;
  const int n0 = (sw & 3) * 128;

  int amask[4];
  const ushort_t* abase[4];
#pragma unroll
  for (int s = 0; s < 4; ++s) {
    int idx = tid + (s << 9);
    int row = idx >> 3, cs = idx & 7;
    int i = row >> 4, j = row & 15;
    int m = 0;
#pragma unroll
    for (int tap = 0; tap < 9; ++tap) {
      int i2 = i + tap / 3 - 1, j2 = j + tap % 3 - 1;
      if (((unsigned)i2 < 16u) & ((unsigned)j2 < 16u)) m |= 1 << tap;
    }
    amask[s] = m;
    abase[s] = X + (size_t)(b * NP + row) * K + ((cs ^ (row & 7)) << 3);
  }
  const ushort_t* bbase[2];
#pragma unroll
  for (int s = 0; s < 2; ++s) {
    int idx = tid + (s << 9);
    int row = idx >> 3, cs = idx & 7;
    bbase[s] = Wp + (size_t)(n0 + row) * K + ((cs ^ (row & 7)) << 3);
  }

  const int sw0 = ((0 + lb) ^ (la & 7)) << 3;
  const int sw1 = ((4 + lb) ^ (la & 7)) << 3;
  const int arow = (wr * 64 + la) * 64;
  const int brow = 16384 + (wc * 64 + la) * 64;

  f32x4 acc[4][4];
#pragma unroll
  for (int i = 0; i < 4; ++i)
#pragma unroll
    for (int j = 0; j < 4; ++j) acc[i][j] = (f32x4){0.f, 0.f, 0.f, 0.f};

  auto tile_par = [&](int t, int& toffA, size_t& wtap, int& tap, int& kc) {
    tap = t / TPT;
    kc  = (t - tap * TPT) << 6;
    int ty = tap / 3;
    toffA = (ty * 16 + (tap - 3 * ty) - 17) * K + kc;
    wtap  = (size_t)tap * NOUT * K + kc;
  };

  // prologue: stage tiles 0 and 1
  {
    int toffA, tap, kc; size_t wtap;
#pragma unroll
    for (int t = 0; t < 2; ++t) {
      tile_par(t, toffA, wtap, tap, kc);
      ushort_t* buf = &lds[t * 24576];
#pragma unroll
      for (int s = 0; s < 4; ++s) {
        const ushort_t* g = ((amask[s] >> tap) & 1) ? abase[s] + toffA : zerot;
        gl_lds16(g, &buf[(tid + (s << 9)) * 8]);
      }
#pragma unroll
      for (int s = 0; s < 2; ++s)
        gl_lds16(bbase[s] + wtap, &buf[16384 + (tid + (s << 9)) * 8]);
    }
  }
  asm volatile("s_waitcnt vmcnt(6)" ::: "memory");
  __builtin_amdgcn_s_barrier();

  for (int t = 0; t < NT; ++t) {
    const ushort_t* buf = &lds[(t % 3) * 24576];
    const int t2 = t + 2;
    const bool do_stage = t2 < NT;
    int toffA2 = 0, tap2 = 0, kc2 = 0; size_t wtap2 = 0;
    ushort_t* buf2 = &lds[0];
    if (do_stage) {
      tile_par(t2, toffA2, wtap2, tap2, kc2);
      buf2 = &lds[(t2 % 3) * 24576];
    }

    bf16x8 Af[4][2], Bf[4][2];
    // ---- P0: read A(mi0-1),B(ni0-1); stage A slots 0-1; 8 MFMA ------------
    Af[0][0] = *(const bf16x8*)&buf[arow + 0 * 1024 + sw0];
    Af[0][1] = *(const bf16x8*)&buf[arow + 0 * 1024 + sw1];
    Af[1][0] = *(const bf16x8*)&buf[arow + 1 * 1024 + sw0];
    Af[1][1] = *(const bf16x8*)&buf[arow + 1 * 1024 + sw1];
    Bf[0][0] = *(const bf16x8*)&buf[brow + 0 * 1024 + sw0];
    Bf[0][1] = *(const bf16x8*)&buf[brow + 0 * 1024 + sw1];
    Bf[1][0] = *(const bf16x8*)&buf[brow + 1 * 1024 + sw0];
    Bf[1][1] = *(const bf16x8*)&buf[brow + 1 * 1024 + sw1];
    if (do_stage) {
#pragma unroll
      for (int s = 0; s < 2; ++s) {
        const ushort_t* g = ((amask[s] >> tap2) & 1) ? abase[s] + toffA2 : zerot;
        gl_lds16(g, &buf2[(tid + (s << 9)) * 8]);
      }
    }
    __builtin_amdgcn_s_barrier();
    asm volatile("s_waitcnt lgkmcnt(0)" ::: "memory");
    __builtin_amdgcn_sched_barrier(0);
    __builtin_amdgcn_s_setprio(1);
    acc[0][0] = mfma16(Af[0][0], Bf[0][0], acc[0][0]);
    acc[0][1] = mfma16(Af[0][0], Bf[1][0], acc[0][1]);
    acc[1][0] = mfma16(Af[1][0], Bf[0][0], acc[1][0]);
    acc[1][1] = mfma16(Af[1][0], Bf[1][0], acc[1][1]);
    acc[0][0] = mfma16(Af[0][1], Bf[0][1], acc[0][0]);
    acc[0][1] = mfma16(Af[0][1], Bf[1][1], acc[0][1]);
    acc[1][0] = mfma16(Af[1][1], Bf[0][1], acc[1][0]);
    acc[1][1] = mfma16(Af[1][1], Bf[1][1], acc[1][1]);
    __builtin_amdgcn_s_setprio(0);
    // ---- P1: read A(mi2-3); stage A slots 2-3; 8 MFMA ---------------------
    Af[2][0] = *(const bf16x8*)&buf[arow + 2 * 1024 + sw0];
    Af[2][1] = *(const bf16x8*)&buf[arow + 2 * 1024 + sw1];
    Af[3][0] = *(const bf16x8*)&buf[arow + 3 * 1024 + sw0];
    Af[3][1] = *(const bf16x8*)&buf[arow + 3 * 1024 + sw1];
    if (do_stage) {
#pragma unroll
      for (int s = 2; s < 4; ++s) {
        const ushort_t* g = ((amask[s] >> tap2) & 1) ? abase[s] + toffA2 : zerot;
        gl_lds16(g, &buf2[(tid + (s << 9)) * 8]);
      }
    }
    __builtin_amdgcn_s_barrier();
    asm volatile("s_waitcnt lgkmcnt(0)" ::: "memory");
    __builtin_amdgcn_sched_barrier(0);
    __builtin_amdgcn_s_setprio(1);
    acc[2][0] = mfma16(Af[2][0], Bf[0][0], acc[2][0]);
    acc[2][1] = mfma16(Af[2][0], Bf[1][0], acc[2][1]);
    acc[3][0] = mfma16(Af[3][0], Bf[0][0], acc[3][0]);
    acc[3][1] = mfma16(Af[3][0], Bf[1][0], acc[3][1]);
    acc[2][0] = mfma16(Af[2][1], Bf[0][1], acc[2][0]);
    acc[2][1] = mfma16(Af[2][1], Bf[1][1], acc[2][1]);
    acc[3][0] = mfma16(Af[3][1], Bf[0][1], acc[3][0]);
    acc[3][1] = mfma16(Af[3][1], Bf[1][1], acc[3][1]);
    __builtin_amdgcn_s_setprio(0);
    // ---- P2: read B(ni2-3); stage B slots 0-1; 8 MFMA ---------------------
    Bf[2][0] = *(const bf16x8*)&buf[brow + 2 * 1024 + sw0];
    Bf[2][1] = *(const bf16x8*)&buf[brow + 2 * 1024 + sw1];
    Bf[3][0] = *(const bf16x8*)&buf[brow + 3 * 1024 + sw0];
    Bf[3][1] = *(const bf16x8*)&buf[brow + 3 * 1024 + sw1];
    if (do_stage) {
#pragma unroll
      for (int s = 0; s < 2; ++s)
        gl_lds16(bbase[s] + wtap2, &buf2[16384 + (tid + (s << 9)) * 8]);
    }
    __builtin_amdgcn_s_barrier();
    asm volatile("s_waitcnt lgkmcnt(0)" ::: "memory");
    __builtin_amdgcn_sched_barrier(0);
    __builtin_amdgcn_s_setprio(1);
    acc[0][2] = mfma16(Af[0][0], Bf[2][0], acc[0][2]);
    acc[0][3] = mfma16(Af[0][0], Bf[3][0], acc[0][3]);
    acc[1][2] = mfma16(Af[1][0], Bf[2][0], acc[1][2]);
    acc[1][3] = mfma16(Af[1][0], Bf[3][0], acc[1][3]);
    acc[0][2] = mfma16(Af[0][1], Bf[2][1], acc[0][2]);
    acc[0][3] = mfma16(Af[0][1], Bf[3][1], acc[0][3]);
    acc[1][2] = mfma16(Af[1][1], Bf[2][1], acc[1][2]);
    acc[1][3] = mfma16(Af[1][1], Bf[3][1], acc[1][3]);
    __builtin_amdgcn_s_setprio(0);
    // ---- P3: 8 MFMA; counted vmcnt; tile boundary barrier -----------------
    __builtin_amdgcn_s_setprio(1);
    acc[2][2] = mfma16(Af[2][0], Bf[2][0], acc[2][2]);
    acc[2][3] = mfma16(Af[2][0], Bf[3][0], acc[2][3]);
    acc[3][2] = mfma16(Af[3][0], Bf[2][0], acc[3][2]);
    acc[3][3] = mfma16(Af[3][0], Bf[3][0], acc[3][3]);
    acc[2][2] = mfma16(Af[2][1], Bf[2][1], acc[2][2]);
    acc[2][3] = mfma16(Af[2][1], Bf[3][1], acc[2][3]);
    acc[3][2] = mfma16(Af[3][1], Bf[2][1], acc[3][2]);
    acc[3][3] = mfma16(Af[3][1], Bf[3][1], acc[3][3]);
    __builtin_amdgcn_s_setprio(0);
    if (do_stage) asm volatile("s_waitcnt vmcnt(6)" ::: "memory");
    else          asm volatile("s_waitcnt vmcnt(0)" ::: "memory");
    __builtin_amdgcn_s_barrier();
  }

  // epilogue: bias + Y write + fused BN stats (shuffle over lb, atomics)
#pragma unroll
  for (int ni = 0; ni < 4; ++ni) {
    int col = n0 + wc * 64 + ni * 16 + la;
    float bv = bias[col];
    float s = 0.f, qq = 0.f;
#pragma unroll
    for (int mi = 0; mi < 4; ++mi) {
      int row = b * NP + wr * 64 + mi * 16 + lb * 4;
#pragma unroll
      for (int r = 0; r < 4; ++r) {
        float v = acc[mi][ni][r] + bv;
        Y[(size_t)(row + r) * NOUT + col] = v;
        s += v; qq += v * v;
      }
    }
    s  += __shfl_xor(s, 16);  s  += __shfl_xor(s, 32);
    qq += __shfl_xor(qq, 16); qq += __shfl_xor(qq, 32);
    if (lb == 0) {
      atomicAdd(&st[col], s);
      atomicAdd(&st[512 + col], qq);
    }
  }
}

// ---------------------------------------------------------------------------
// BN apply + relu + bf16 cast, same-layout output [m][c].
// ---------------------------------------------------------------------------
__global__ __launch_bounds__(256) void bn_apply(
    const float* __restrict__ Y, const float* __restrict__ st,
    const float* __restrict__ g, const float* __restrict__ be,
    ushort_t* __restrict__ Xo)
{
  const int idx = blockIdx.x * 256 + threadIdx.x;
  const float4 y = *(const float4*)(Y + (size_t)idx * 4);
  const int c0 = (idx * 4) & 511;
  const float yv[4] = {y.x, y.y, y.z, y.w};
  u16x4 pk;
#pragma unroll
  for (int q = 0; q < 4; ++q) {
    int c = c0 + q;
    float mu  = st[c] * (1.f / 16384.f);
    float var = st[512 + c] * (1.f / 16384.f) - mu * mu;
    float s = rsqrtf(var + 1e-5f) * g[c];
    pk[q] = f2bf(fmaxf((yv[q] - mu) * s + be[c], 0.f));
  }
  *(u16x4*)(Xo + (size_t)idx * 4) = pk;
}

// ---------------------------------------------------------------------------
// BN apply + relu + bf16, transposed to FC layout Xf[b][c*256+ij].
// ---------------------------------------------------------------------------
__global__ __launch_bounds__(256) void bn_apply_t(
    const float* __restrict__ Y, const float* __restrict__ st,
    const float* __restrict__ g, const float* __restrict__ be,
    ushort_t* __restrict__ Xf)
{
  __shared__ ushort_t T[64][65];
  const int c0  = blockIdx.x * 64;
  const int ij0 = blockIdx.y * 64;
  const int b   = blockIdx.z;
  const int tid = threadIdx.x;

#pragma unroll
  for (int it = 0; it < 16; ++it) {
    int e = it * 256 + tid;
    int ij = e >> 6, c = e & 63;
    int cg = c0 + c;
    float y = Y[((size_t)(b * NP + ij0 + ij)) * NOUT + cg];
    float mu  = st[cg] * (1.f / 16384.f);
    float var = st[512 + cg] * (1.f / 16384.f) - mu * mu;
    float s = rsqrtf(var + 1e-5f) * g[cg];
    T[ij][c] = f2bf(fmaxf((y - mu) * s + be[cg], 0.f));
  }
  __syncthreads();
#pragma unroll
  for (int it = 0; it < 16; ++it) {
    int e = it * 256 + tid;
    int cr = e >> 6, ijc = e & 63;
    Xf[(size_t)b * KFC + (size_t)(c0 + cr) * NP + ij0 + ijc] = T[ijc][cr];
  }
}

// ---------------------------------------------------------------------------
// FC1: (64 x 131072) bf16 @ (1024 x 131072)^T, split-K slice stores.
// grid (16, 32), block 256; block writes its 64x64 partial to slice y.
// ---------------------------------------------------------------------------
__device__ __forceinline__ u16x8 pack8(float4 a, float4 b) {
  u16x8 r;
  r[0] = f2bf(a.x); r[1] = f2bf(a.y); r[2] = f2bf(a.z); r[3] = f2bf(a.w);
  r[4] = f2bf(b.x); r[5] = f2bf(b.y); r[6] = f2bf(b.z); r[7] = f2bf(b.w);
  return r;
}

__global__ __launch_bounds__(256) void fc1_gemm(
    const ushort_t* __restrict__ Xf, const float* __restrict__ Wf1,
    float* __restrict__ hacc)
{
  __shared__ ushort_t As[64 * 64];
  __shared__ ushort_t Bs[64 * 64];
  const int tid = threadIdx.x, lane = tid & 63, wave = tid >> 6;
  const int la = lane & 15, lb = lane >> 4;
  const int f0 = blockIdx.x * 64;
  const int k0 = blockIdx.y * 4096;

  f32x4 acc[4];
#pragma unroll
  for (int i = 0; i < 4; ++i) acc[i] = (f32x4){0.f, 0.f, 0.f, 0.f};

  const ushort_t* xrow[2];
#pragma unroll
  for (int s = 0; s < 2; ++s) {
    int idx = tid + (s << 8);
    xrow[s] = Xf + (size_t)(idx >> 3) * KFC + k0 + (idx & 7) * 8;
  }
  const int brow = tid >> 2, kseg = (tid & 3) * 16;
  const float* wrow = Wf1 + (size_t)(f0 + brow) * KFC + k0 + kseg;

  for (int kc = 0; kc < 4096; kc += 64) {
#pragma unroll
    for (int s = 0; s < 2; ++s) {
      int idx = tid + (s << 8);
      gl_lds16(xrow[s] + kc, &As[idx * 8]);
    }
    float4 w0 = *(const float4*)(wrow + kc);
    float4 w1 = *(const float4*)(wrow + kc + 4);
    float4 w2 = *(const float4*)(wrow + kc + 8);
    float4 w3 = *(const float4*)(wrow + kc + 12);
    *(u16x8*)&Bs[brow * 64 + kseg]     = pack8(w0, w1);
    *(u16x8*)&Bs[brow * 64 + kseg + 8] = pack8(w2, w3);
    __syncthreads();
#pragma unroll
    for (int kk = 0; kk < 2; ++kk) {
      bf16x8 bfv = *(const bf16x8*)&Bs[(wave * 16 + la) * 64 + kk * 32 + lb * 8];
#pragma unroll
      for (int mi = 0; mi < 4; ++mi) {
        bf16x8 av = *(const bf16x8*)&As[(mi * 16 + la) * 64 + kk * 32 + lb * 8];
        acc[mi] = mfma16(av, bfv, acc[mi]);
      }
    }
    __syncthreads();
  }

  float* slice = hacc + (size_t)blockIdx.y * NB * NF;
#pragma unroll
  for (int mi = 0; mi < 4; ++mi) {
    int row = mi * 16 + lb * 4;
#pragma unroll
    for (int r = 0; r < 4; ++r)
      slice[(size_t)(row + r) * NF + f0 + wave * 16 + la] = acc[mi][r];
  }
}

// ---------------------------------------------------------------------------
// FC2 + bias/relu; sums the 32 fc1 k-slices. grid 64, block 256.
// ---------------------------------------------------------------------------
__global__ __launch_bounds__(256) void fc2_out(
    const float* __restrict__ hacc, const float* __restrict__ bf1,
    const float* __restrict__ Wf2, const float* __restrict__ bf2,
    float* __restrict__ out)
{
  const int b = blockIdx.x, tid = threadIdx.x;
  float a[8];
#pragma unroll
  for (int o = 0; o < 8; ++o) a[o] = 0.f;
  for (int f = tid; f < NF; f += 256) {
    float hv = bf1[f];
#pragma unroll 4
    for (int s = 0; s < KSPL; ++s)
      hv += hacc[((size_t)s * NB + b) * NF + f];
    hv = fmaxf(hv, 0.f);
#pragma unroll
    for (int o = 0; o < 8; ++o) a[o] += hv * Wf2[o * NF + f];
  }
  __shared__ float red[8][256];
#pragma unroll
  for (int o = 0; o < 8; ++o) red[o][tid] = a[o];
  __syncthreads();
  for (int s = 128; s > 0; s >>= 1) {
    if (tid < s) {
#pragma unroll
      for (int o = 0; o < 8; ++o) red[o][tid] += red[o][tid + s];
    }
    __syncthreads();
  }
  if (tid < 8) out[b * 8 + tid] = red[tid][0] + bf2[tid];
}

// ---------------------------------------------------------------------------
extern "C" void kernel_launch(void* const* d_in, const int* in_sizes, int n_in,
                              void* d_out, int out_size, void* d_ws, size_t ws_size,
                              hipStream_t stream) {
  const float* f1  = (const float*)d_in[0];
  const float* f2  = (const float*)d_in[1];
  const float* W1  = (const float*)d_in[2];
  const float* b1  = (const float*)d_in[3];
  const float* g1  = (const float*)d_in[4];
  const float* be1 = (const float*)d_in[5];
  const float* W2  = (const float*)d_in[6];
  const float* b2  = (const float*)d_in[7];
  const float* g2  = (const float*)d_in[8];
  const float* be2 = (const float*)d_in[9];
  const float* W3  = (const float*)d_in[10];
  const float* b3  = (const float*)d_in[11];
  const float* g3  = (const float*)d_in[12];
  const float* be3 = (const float*)d_in[13];
  const float* Wf1 = (const float*)d_in[14];
  const float* bf1 = (const float*)d_in[15];
  const float* Wf2 = (const float*)d_in[16];
  const float* bf2 = (const float*)d_in[17];
  float* out = (float*)d_out;

  char* ws = (char*)d_ws;
  size_t off = 0;
  auto alloc = [&](size_t bytes) -> void* {
    void* p = ws + off;
    off += (bytes + 255) & ~(size_t)255;
    return p;
  };

  // zeroed region: zero tile + BN stats only
  ushort_t* zerot = (ushort_t*)alloc(256);
  float* st1  = (float*)alloc(1024 * 4);
  float* st2  = (float*)alloc(1024 * 4);
  float* st3  = (float*)alloc(1024 * 4);
  const size_t zero_bytes = off;

  float* hacc = (float*)alloc((size_t)KSPL * NB * NF * 4);  // fully written
  const size_t SZ_AT   = (size_t)NB * NP * NC * 2;
  const size_t SZ_COST = (size_t)NB * NP * KP1 * 2;
  const size_t SZ_WP1  = (size_t)9 * NOUT * KP1 * 2;
  const size_t SZ_WP23 = (size_t)9 * NOUT * 512 * 2;
  ushort_t* AT    = (ushort_t*)alloc(SZ_AT);
  ushort_t* N2T   = (ushort_t*)alloc(SZ_AT);
  ushort_t* costT = (ushort_t*)alloc(SZ_COST);
  ushort_t* Wp1   = (ushort_t*)alloc(SZ_WP1);
  ushort_t* Wp2   = (ushort_t*)alloc(SZ_WP23);
  ushort_t* Wp3   = (ushort_t*)alloc(SZ_WP23);
  float*    Ybuf  = (float*)alloc((size_t)NROWS * NOUT * 4);
  ushort_t* Xbuf  = (ushort_t*)alloc((size_t)NROWS * NOUT * 2);
  ushort_t* Xf    = (ushort_t*)alloc((size_t)NB * KFC * 2);

  hipMemsetAsync(ws, 0, zero_bytes, stream);
  hipMemsetAsync(costT, 0, SZ_COST, stream);

  l2norm_t<<<dim3(64, 2), 256, 0, stream>>>(f1, f2, AT, N2T);

  pack_w<<<(9 * NOUT * KP1 + 255) / 256, 256, 0, stream>>>(W1, Wp1, 1089, KP1, 9 * NOUT * KP1);
  pack_w<<<(9 * NOUT * 512 + 255) / 256, 256, 0, stream>>>(W2, Wp2, 512, 512, 9 * NOUT * 512);
  pack_w<<<(9 * NOUT * 512 + 255) / 256, 256, 0, stream>>>(W3, Wp3, 512, 512, 9 * NOUT * 512);

  cv_gemm<<<dim3(18, 2, 64), 256, 0, stream>>>(AT, N2T, costT, zerot);

  conv_gemm8<<<256, 512, 0, stream>>>(costT, Wp1, b1, Ybuf, st1, KP1, 18, 162, zerot);
  bn_apply<<<8192, 256, 0, stream>>>(Ybuf, st1, g1, be1, Xbuf);

  conv_gemm8<<<256, 512, 0, stream>>>(Xbuf, Wp2, b2, Ybuf, st2, 512, 8, 72, zerot);
  bn_apply<<<8192, 256, 0, stream>>>(Ybuf, st2, g2, be2, Xbuf);

  conv_gemm8<<<256, 512, 0, stream>>>(Xbuf, Wp3, b3, Ybuf, st3, 512, 8, 72, zerot);
  bn_apply_t<<<dim3(8, 4, 64), 256, 0, stream>>>(Ybuf, st3, g3, be3, Xf);

  fc1_gemm<<<dim3(16, KSPL), 256, 0, stream>>>(Xf, Wf1, hacc);
  fc2_out<<<64, 256, 0, stream>>>(hacc, bf1, Wf2, bf2, out);

  (void)in_sizes; (void)n_in; (void)out_size; (void)ws_size;
}

// Round 5
// 621.234 us; speedup vs baseline: 1.2941x; 1.0154x over previous
//
#include <hip/hip_runtime.h>
#include <hip/hip_bf16.h>
#include <stdint.h>

// ---------------------------------------------------------------------------
// RegressionNet: cost-volume + 3x conv-BN-relu + 2x FC, bf16 MFMA pipeline.
// R4: convs -> 256x256 tile (AI 87->131 FLOP/B), 2-way K-split (256 blocks),
//     dbuf 128KB LDS, 4 phases/tile with derived counted vmcnt (6/4/-/2),
//     partial-Y bf16 halves + bn_stat2/bn_apply2 passes.
// ---------------------------------------------------------------------------

typedef unsigned short ushort_t;
typedef __attribute__((ext_vector_type(8))) short     bf16x8;
typedef __attribute__((ext_vector_type(8))) unsigned short u16x8;
typedef __attribute__((ext_vector_type(4))) unsigned short u16x4;
typedef __attribute__((ext_vector_type(4))) float     f32x4;

#define NB   64
#define NC   256
#define NP   256
#define KCV  256
#define KP1  1152
#define NOUT 512
#define NROWS 16384
#define KFC  131072
#define NF   1024
#define KSPL 32      // fc1 k-splits

__device__ __forceinline__ unsigned short f2bf(float x) {
  union { float f; unsigned u; } c; c.f = x;
  unsigned r = c.u + 0x7FFFu + ((c.u >> 16) & 1u);
  return (unsigned short)(r >> 16);
}
__device__ __forceinline__ float b2f(unsigned short u) {
  union { unsigned u; float f; } c; c.u = ((unsigned)u) << 16; return c.f;
}

__device__ __forceinline__ void gl_lds16(const void* g, void* l) {
  __builtin_amdgcn_global_load_lds(
      (const __attribute__((address_space(1))) unsigned int*)g,
      (__attribute__((address_space(3))) unsigned int*)l, 16, 0, 0);
}

__device__ __forceinline__ f32x4 mfma16(bf16x8 a, bf16x8 b, f32x4 c) {
  return __builtin_amdgcn_mfma_f32_16x16x32_bf16(a, b, c, 0, 0, 0);
}

// ---------------------------------------------------------------------------
// l2-normalize over channels; write pos-major bf16 [b][pos][c].
// ---------------------------------------------------------------------------
__global__ __launch_bounds__(256) void l2norm_t(
    const float* __restrict__ f1, const float* __restrict__ f2,
    ushort_t* __restrict__ AT, ushort_t* __restrict__ N2T)
{
  const float* src = blockIdx.y ? f2 : f1;
  ushort_t*    dst = blockIdx.y ? N2T : AT;
  const int b = blockIdx.x, t = threadIdx.x;
  const float* sb = src + (size_t)b * NC * NP;
  float sq = 0.f;
  for (int c = 0; c < NC; ++c) { float v = sb[c * NP + t]; sq += v * v; }
  float sc = 1.f / fmaxf(sqrtf(sq), 1e-12f);
  ushort_t* db = dst + ((size_t)b * NP + t) * NC;
  for (int c0 = 0; c0 < NC; c0 += 8) {
    u16x8 pk;
#pragma unroll
    for (int q = 0; q < 8; ++q) pk[q] = f2bf(sb[(c0 + q) * NP + t] * sc);
    *(u16x8*)(db + c0) = pk;
  }
}

// ---------------------------------------------------------------------------
// Pack conv weights (OUT, Cin, 3, 3) fp32 -> [tap][out][cin(pad Kp)] bf16.
// ---------------------------------------------------------------------------
__global__ __launch_bounds__(256) void pack_w(
    const float* __restrict__ W, ushort_t* __restrict__ Wp,
    int Cin, int Kp, int total)
{
  int p = blockIdx.x * 256 + threadIdx.x;
  if (p >= total) return;
  int tap = p / (NOUT * Kp);
  int rem = p - tap * (NOUT * Kp);
  int o   = rem / Kp;
  int cin = rem - o * Kp;
  float v = (cin < Cin) ? W[((size_t)o * Cin + cin) * 9 + tap] : 0.f;
  Wp[p] = f2bf(v);
}

// ---------------------------------------------------------------------------
// Cost volume: per-b GEMM (pos x uv over channels), band-gather epilogue.
// ---------------------------------------------------------------------------
__global__ __launch_bounds__(256) void cv_gemm(
    const ushort_t* __restrict__ AT,
    const ushort_t* __restrict__ N2T,
    ushort_t* __restrict__ costT,
    const ushort_t* __restrict__ zerot)
{
  __shared__ ushort_t As[128 * 64];
  __shared__ ushort_t Bs[128 * 64];
  const int tid = threadIdx.x, lane = tid & 63, wave = tid >> 6;
  const int wr = wave >> 1, wc = wave & 1;
  const int la = lane & 15, lb = lane >> 4;
  const int b  = blockIdx.z;
  const int m0 = blockIdx.y * 128;
  const int n0 = blockIdx.x * 128;

  {
    const int iMin = blockIdx.y * 8, iMax = iMin + 7;
    const int uMin = n0 / 48, uMax = (n0 + 127) / 48;
    if (uMax < iMin || uMin > iMax + 32) return;
  }

  f32x4 acc[4][4];
#pragma unroll
  for (int i = 0; i < 4; ++i)
#pragma unroll
    for (int j = 0; j < 4; ++j) acc[i][j] = (f32x4){0.f, 0.f, 0.f, 0.f};

  const ushort_t* srcA[4];
  const ushort_t* srcB[4];
#pragma unroll
  for (int s = 0; s < 4; ++s) {
    int idx = tid + (s << 8);
    int row = idx >> 3, c16 = idx & 7;
    srcA[s] = AT + ((size_t)b * NP + m0 + row) * NC + c16 * 8;
    int uv = n0 + row;
    int u = uv / 48, v = uv - u * 48;
    int oi = u - 16, oj = v - 16;
    bool val = ((unsigned)oi < 16u) & ((unsigned)oj < 16u);
    srcB[s] = val ? (N2T + ((size_t)b * NP + oi * 16 + oj) * NC + c16 * 8)
                  : (const ushort_t*)0;
  }

  for (int kc = 0; kc < KCV; kc += 64) {
#pragma unroll
    for (int s = 0; s < 4; ++s) {
      int idx = tid + (s << 8);
      gl_lds16(srcA[s] + kc, &As[idx * 8]);
      const ushort_t* g = srcB[s] ? srcB[s] + kc : zerot;
      gl_lds16(g, &Bs[idx * 8]);
    }
    __syncthreads();
#pragma unroll
    for (int kk = 0; kk < 2; ++kk) {
      bf16x8 af[4], bfv[4];
#pragma unroll
      for (int mi = 0; mi < 4; ++mi)
        af[mi] = *(const bf16x8*)&As[(wr * 64 + mi * 16 + la) * 64 + kk * 32 + lb * 8];
#pragma unroll
      for (int ni = 0; ni < 4; ++ni)
        bfv[ni] = *(const bf16x8*)&Bs[(wc * 64 + ni * 16 + la) * 64 + kk * 32 + lb * 8];
#pragma unroll
      for (int mi = 0; mi < 4; ++mi)
#pragma unroll
        for (int ni = 0; ni < 4; ++ni)
          acc[mi][ni] = mfma16(af[mi], bfv[ni], acc[mi][ni]);
    }
    __syncthreads();
  }

  const float sc = 1.f / 256.f;
#pragma unroll
  for (int ni = 0; ni < 4; ++ni) {
    int uv = n0 + wc * 64 + ni * 16 + la;
    int u = uv / 48, v = uv - u * 48;
#pragma unroll
    for (int mi = 0; mi < 4; ++mi) {
      int ij = m0 + wr * 64 + mi * 16 + lb * 4;
#pragma unroll
      for (int r = 0; r < 4; ++r) {
        int ijr = ij + r;
        int i = ijr >> 4, j = ijr & 15;
        int dy = u - i, dx = v - j;
        if ((unsigned)dy < 33u && (unsigned)dx < 33u) {
          float vv = acc[mi][ni][r] * sc;
          vv = vv > 0.f ? vv : 0.01f * vv;
          costT[((size_t)b * NP + ijr) * KP1 + dy * 33 + dx] = f2bf(vv);
        }
      }
    }
  }
}

// ---------------------------------------------------------------------------
// Conv 3x3, 256x256x64 tile, 2-way K-split, dbuf LDS, 4 phases/tile.
// Block 512 = 8 waves (2M x 4N); per-wave 128x64 out (acc[8][4]).
// A slots: s0=rows0-63, s1=128-191, s2=64-127, s3=192-255 (phase-aligned).
// B slots: rB = (s&1)*128 + (loc>>5)*64 + (s>>1)*32 + (loc&31).
// Chunk-XOR swizzle on global source; LDS linear (rule #21).
// vmcnt: P0=6, P1=4, P2=none, P3=2 (derived; never 0 mid-loop).
// ---------------------------------------------------------------------------
__global__ __launch_bounds__(512, 1) void conv_gemm256(
    const ushort_t* __restrict__ X, const ushort_t* __restrict__ Wp,
    const float* __restrict__ bias, ushort_t* __restrict__ Y0,
    ushort_t* __restrict__ Y1, const int K, const int TPT, const int NT2,
    const ushort_t* __restrict__ zerot)
{
  __shared__ ushort_t lds[65536];   // 2 x (A 16384 + B 16384) elements
  const int tid = threadIdx.x;
  const int lane = tid & 63, wave = tid >> 6;
  const int wr = wave >> 2, wc = wave & 3;
  const int la = lane & 15, lb = lane >> 4;

  // XCD swizzle: xcd = bid&7 gets contiguous logical chunk; logical L:
  // g = L>>7 (k-group), b = (L&127)>>1, n = L&1.
  const int bid = blockIdx.x;
  const int L = ((bid & 7) << 5) + (bid >> 3);
  const int g = L >> 7;
  const int rem = L & 127;
  const int b = rem >> 1;
  const int n0 = (rem & 1) << 8;
  const int t0 = g * NT2;

  int amask[4];
  const ushort_t* abase[4];
  const ushort_t* bbase[4];
#pragma unroll
  for (int s = 0; s < 4; ++s) {
    int idx = tid + (s << 9);
    int ks = idx & 7, loc = (idx >> 3) & 63;
    int rA = ((s & 1) << 7) + ((s >> 1) << 6) + loc;
    int i = rA >> 4, j = rA & 15;
    int m = 0;
#pragma unroll
    for (int tap = 0; tap < 9; ++tap) {
      int i2 = i + tap / 3 - 1, j2 = j + tap % 3 - 1;
      if (((unsigned)i2 < 16u) & ((unsigned)j2 < 16u)) m |= 1 << tap;
    }
    amask[s] = m;
    abase[s] = X + (size_t)(b * NP + rA) * K + ((ks ^ (rA & 7)) << 3);
    int rB = ((s & 1) << 7) + ((loc >> 5) << 6) + ((s >> 1) << 5) + (loc & 31);
    bbase[s] = Wp + (size_t)(n0 + rB) * K + ((ks ^ (rB & 7)) << 3);
  }

  // read offsets (elements)
  const int ck0 = ((0 + lb) ^ (la & 7)) << 3;
  const int ck1 = ((4 + lb) ^ (la & 7)) << 3;
  const int a_base = wr * 4096 + la * 64;                       // + (mi>>2)*8192 + (mi&3)*1024
  const int b_base = 16384 + (wc >> 1) * 4096 + (wc & 1) * 2048 + la * 64; // + (ni>>1)*8192 + (ni&1)*1024

  f32x4 acc[8][4];
#pragma unroll
  for (int i = 0; i < 8; ++i)
#pragma unroll
    for (int j = 0; j < 4; ++j) acc[i][j] = (f32x4){0.f, 0.f, 0.f, 0.f};

  auto tile_par = [&](int tg, int& toffA, size_t& wtap, int& tap) {
    tap = tg / TPT;
    int kc = (tg - tap * TPT) << 6;
    int ty = tap / 3;
    toffA = (ty * 16 + (tap - 3 * ty) - 17) * K + kc;
    wtap  = (size_t)tap * NOUT * K + kc;
  };

#define STAGE_A(S) { const ushort_t* gp = ((amask[S] >> tapN) & 1) ? abase[S] + toffN : zerot; \
                     gl_lds16(gp, &bufn[(tid + ((S) << 9)) * 8]); }
#define STAGE_B(S) gl_lds16(bbase[S] + wtapN, &bufn[16384 + (tid + ((S) << 9)) * 8]);

#define READ_A03() \
  Af[0][0] = *(const bf16x8*)&buf[a_base + 0    + ck0]; Af[0][1] = *(const bf16x8*)&buf[a_base + 0    + ck1]; \
  Af[1][0] = *(const bf16x8*)&buf[a_base + 1024 + ck0]; Af[1][1] = *(const bf16x8*)&buf[a_base + 1024 + ck1]; \
  Af[2][0] = *(const bf16x8*)&buf[a_base + 2048 + ck0]; Af[2][1] = *(const bf16x8*)&buf[a_base + 2048 + ck1]; \
  Af[3][0] = *(const bf16x8*)&buf[a_base + 3072 + ck0]; Af[3][1] = *(const bf16x8*)&buf[a_base + 3072 + ck1];
#define READ_A47() \
  Af[4][0] = *(const bf16x8*)&buf[a_base + 8192 + 0    + ck0]; Af[4][1] = *(const bf16x8*)&buf[a_base + 8192 + 0    + ck1]; \
  Af[5][0] = *(const bf16x8*)&buf[a_base + 8192 + 1024 + ck0]; Af[5][1] = *(const bf16x8*)&buf[a_base + 8192 + 1024 + ck1]; \
  Af[6][0] = *(const bf16x8*)&buf[a_base + 8192 + 2048 + ck0]; Af[6][1] = *(const bf16x8*)&buf[a_base + 8192 + 2048 + ck1]; \
  Af[7][0] = *(const bf16x8*)&buf[a_base + 8192 + 3072 + ck0]; Af[7][1] = *(const bf16x8*)&buf[a_base + 8192 + 3072 + ck1];
#define READ_B(NOFF) \
  bf00 = *(const bf16x8*)&buf[b_base + (NOFF) + 0    + ck0]; bf01 = *(const bf16x8*)&buf[b_base + (NOFF) + 0    + ck1]; \
  bf10 = *(const bf16x8*)&buf[b_base + (NOFF) + 1024 + ck0]; bf11 = *(const bf16x8*)&buf[b_base + (NOFF) + 1024 + ck1];
#define MFMA_QUAD(MB, N0, N1) \
  acc[MB+0][N0] = mfma16(Af[MB+0][0], bf00, acc[MB+0][N0]); \
  acc[MB+0][N1] = mfma16(Af[MB+0][0], bf10, acc[MB+0][N1]); \
  acc[MB+1][N0] = mfma16(Af[MB+1][0], bf00, acc[MB+1][N0]); \
  acc[MB+1][N1] = mfma16(Af[MB+1][0], bf10, acc[MB+1][N1]); \
  acc[MB+2][N0] = mfma16(Af[MB+2][0], bf00, acc[MB+2][N0]); \
  acc[MB+2][N1] = mfma16(Af[MB+2][0], bf10, acc[MB+2][N1]); \
  acc[MB+3][N0] = mfma16(Af[MB+3][0], bf00, acc[MB+3][N0]); \
  acc[MB+3][N1] = mfma16(Af[MB+3][0], bf10, acc[MB+3][N1]); \
  acc[MB+0][N0] = mfma16(Af[MB+0][1], bf01, acc[MB+0][N0]); \
  acc[MB+0][N1] = mfma16(Af[MB+0][1], bf11, acc[MB+0][N1]); \
  acc[MB+1][N0] = mfma16(Af[MB+1][1], bf01, acc[MB+1][N0]); \
  acc[MB+1][N1] = mfma16(Af[MB+1][1], bf11, acc[MB+1][N1]); \
  acc[MB+2][N0] = mfma16(Af[MB+2][1], bf01, acc[MB+2][N0]); \
  acc[MB+2][N1] = mfma16(Af[MB+2][1], bf11, acc[MB+2][N1]); \
  acc[MB+3][N0] = mfma16(Af[MB+3][1], bf01, acc[MB+3][N0]); \
  acc[MB+3][N1] = mfma16(Af[MB+3][1], bf11, acc[MB+3][N1]);

  // prologue: stage tile0 chunks in phase order A01, A23, B01, B23
  {
    ushort_t* bufn = &lds[0];
    int tapN, toffN; size_t wtapN;
    tile_par(t0, toffN, wtapN, tapN);
    STAGE_A(0) STAGE_A(1) STAGE_A(2) STAGE_A(3)
    STAGE_B(0) STAGE_B(1) STAGE_B(2) STAGE_B(3)
  }
  asm volatile("s_waitcnt vmcnt(2)" ::: "memory");
  __builtin_amdgcn_s_barrier();

  bf16x8 Af[8][2];

  for (int t = 0; t < NT2 - 1; ++t) {
    const ushort_t* buf = &lds[(t & 1) << 15];
    ushort_t* bufn = &lds[((t + 1) & 1) << 15];
    int tapN, toffN; size_t wtapN;
    tile_par(t0 + t + 1, toffN, wtapN, tapN);
    bf16x8 bf00, bf01, bf10, bf11;

    // ---- P0: read A0-3 + B(n0,n1); stage next A01 ----
    READ_A03()
    READ_B(0)
    STAGE_A(0) STAGE_A(1)
    asm volatile("s_waitcnt vmcnt(6)" ::: "memory");
    __builtin_amdgcn_s_barrier();
    asm volatile("s_waitcnt lgkmcnt(0)" ::: "memory");
    __builtin_amdgcn_sched_barrier(0);
    __builtin_amdgcn_s_setprio(1);
    MFMA_QUAD(0, 0, 1)
    __builtin_amdgcn_s_setprio(0);

    // ---- P1: read A4-7 + B(n0,n1) again; stage next A23 ----
    READ_A47()
    READ_B(0)
    STAGE_A(2) STAGE_A(3)
    asm volatile("s_waitcnt vmcnt(4)" ::: "memory");
    __builtin_amdgcn_s_barrier();
    asm volatile("s_waitcnt lgkmcnt(0)" ::: "memory");
    __builtin_amdgcn_sched_barrier(0);
    __builtin_amdgcn_s_setprio(1);
    MFMA_QUAD(4, 0, 1)
    __builtin_amdgcn_s_setprio(0);

    // ---- P2: read B(n2,n3); stage next B01 ----
    READ_B(8192)
    STAGE_B(0) STAGE_B(1)
    __builtin_amdgcn_s_barrier();
    asm volatile("s_waitcnt lgkmcnt(0)" ::: "memory");
    __builtin_amdgcn_sched_barrier(0);
    __builtin_amdgcn_s_setprio(1);
    MFMA_QUAD(0, 2, 3)
    __builtin_amdgcn_s_setprio(0);

    // ---- P3: read B(n2,n3) again; stage next B23 ----
    READ_B(8192)
    STAGE_B(2) STAGE_B(3)
    asm volatile("s_waitcnt vmcnt(2)" ::: "memory");
    __builtin_amdgcn_s_barrier();
    asm volatile("s_waitcnt lgkmcnt(0)" ::: "memory");
    __builtin_amdgcn_sched_barrier(0);
    __builtin_amdgcn_s_setprio(1);
    MFMA_QUAD(4, 2, 3)
    __builtin_amdgcn_s_setprio(0);
  }

  // ---- tail tile (no staging) ----
  {
    const ushort_t* buf = &lds[((NT2 - 1) & 1) << 15];
    bf16x8 bf00, bf01, bf10, bf11;
    asm volatile("s_waitcnt vmcnt(0)" ::: "memory");
    __builtin_amdgcn_s_barrier();
    READ_A03()
    READ_B(0)
    asm volatile("s_waitcnt lgkmcnt(0)" ::: "memory");
    __builtin_amdgcn_sched_barrier(0);
    MFMA_QUAD(0, 0, 1)
    READ_A47()
    asm volatile("s_waitcnt lgkmcnt(0)" ::: "memory");
    __builtin_amdgcn_sched_barrier(0);
    MFMA_QUAD(4, 0, 1)
    READ_B(8192)
    asm volatile("s_waitcnt lgkmcnt(0)" ::: "memory");
    __builtin_amdgcn_sched_barrier(0);
    MFMA_QUAD(0, 2, 3)
    MFMA_QUAD(4, 2, 3)
  }

  // epilogue: bias/2 + bf16 partial-Y store
  ushort_t* Yh = g ? Y1 : Y0;
#pragma unroll
  for (int ni = 0; ni < 4; ++ni) {
    int col = n0 + wc * 64 + ni * 16 + la;
    float bv = 0.5f * bias[col];
#pragma unroll
    for (int mi = 0; mi < 8; ++mi) {
      int row = b * NP + wr * 128 + mi * 16 + lb * 4;
#pragma unroll
      for (int r = 0; r < 4; ++r)
        Yh[(size_t)(row + r) * NOUT + col] = f2bf(acc[mi][ni][r] + bv);
    }
  }
#undef STAGE_A
#undef STAGE_B
#undef READ_A03
#undef READ_A47
#undef READ_B
#undef MFMA_QUAD
}

// ---------------------------------------------------------------------------
// BN stats from the two bf16 partial halves. grid 512 x block 512.
// ---------------------------------------------------------------------------
__global__ __launch_bounds__(512) void bn_stat2(
    const ushort_t* __restrict__ Y0, const ushort_t* __restrict__ Y1,
    float* __restrict__ st)
{
  const int col = threadIdx.x;
  const size_t base = (size_t)blockIdx.x * 32 * NOUT;
  float s = 0.f, q = 0.f;
  for (int r = 0; r < 32; ++r) {
    float y = b2f(Y0[base + r * NOUT + col]) + b2f(Y1[base + r * NOUT + col]);
    s += y; q += y * y;
  }
  atomicAdd(&st[col], s);
  atomicAdd(&st[512 + col], q);
}

// ---------------------------------------------------------------------------
// BN apply (sum halves) + relu + bf16, layout [m][c]. grid 4096, block 256.
// ---------------------------------------------------------------------------
__global__ __launch_bounds__(256) void bn_apply2(
    const ushort_t* __restrict__ Y0, const ushort_t* __restrict__ Y1,
    const float* __restrict__ st, const float* __restrict__ g,
    const float* __restrict__ be, ushort_t* __restrict__ Xo)
{
  const size_t idx = (size_t)blockIdx.x * 256 + threadIdx.x;
  u16x8 a = *(const u16x8*)(Y0 + idx * 8);
  u16x8 c = *(const u16x8*)(Y1 + idx * 8);
  const int c0 = (int)((idx * 8) & 511);
  u16x8 pk;
#pragma unroll
  for (int q = 0; q < 8; ++q) {
    int cc = c0 + q;
    float y = b2f(a[q]) + b2f(c[q]);
    float mu  = st[cc] * (1.f / 16384.f);
    float var = st[512 + cc] * (1.f / 16384.f) - mu * mu;
    float s = rsqrtf(var + 1e-5f) * g[cc];
    pk[q] = f2bf(fmaxf((y - mu) * s + be[cc], 0.f));
  }
  *(u16x8*)(Xo + idx * 8) = pk;
}

// ---------------------------------------------------------------------------
// BN apply + relu + bf16, transposed to FC layout Xf[b][c*256+ij].
// ---------------------------------------------------------------------------
__global__ __launch_bounds__(256) void bn_apply2_t(
    const ushort_t* __restrict__ Y0, const ushort_t* __restrict__ Y1,
    const float* __restrict__ st, const float* __restrict__ g,
    const float* __restrict__ be, ushort_t* __restrict__ Xf)
{
  __shared__ ushort_t T[64][65];
  const int c0  = blockIdx.x * 64;
  const int ij0 = blockIdx.y * 64;
  const int b   = blockIdx.z;
  const int tid = threadIdx.x;

#pragma unroll
  for (int it = 0; it < 16; ++it) {
    int e = it * 256 + tid;
    int ij = e >> 6, c = e & 63;
    int cg = c0 + c;
    size_t off = ((size_t)(b * NP + ij0 + ij)) * NOUT + cg;
    float y = b2f(Y0[off]) + b2f(Y1[off]);
    float mu  = st[cg] * (1.f / 16384.f);
    float var = st[512 + cg] * (1.f / 16384.f) - mu * mu;
    float s = rsqrtf(var + 1e-5f) * g[cg];
    T[ij][c] = f2bf(fmaxf((y - mu) * s + be[cg], 0.f));
  }
  __syncthreads();
#pragma unroll
  for (int it = 0; it < 16; ++it) {
    int e = it * 256 + tid;
    int cr = e >> 6, ijc = e & 63;
    Xf[(size_t)b * KFC + (size_t)(c0 + cr) * NP + ij0 + ijc] = T[ijc][cr];
  }
}

// ---------------------------------------------------------------------------
// FC1: (64 x 131072) bf16 @ (1024 x 131072)^T, split-K slice stores.
// ---------------------------------------------------------------------------
__device__ __forceinline__ u16x8 pack8(float4 a, float4 b) {
  u16x8 r;
  r[0] = f2bf(a.x); r[1] = f2bf(a.y); r[2] = f2bf(a.z); r[3] = f2bf(a.w);
  r[4] = f2bf(b.x); r[5] = f2bf(b.y); r[6] = f2bf(b.z); r[7] = f2bf(b.w);
  return r;
}

__global__ __launch_bounds__(256) void fc1_gemm(
    const ushort_t* __restrict__ Xf, const float* __restrict__ Wf1,
    float* __restrict__ hacc)
{
  __shared__ ushort_t As[64 * 64];
  __shared__ ushort_t Bs[64 * 64];
  const int tid = threadIdx.x, lane = tid & 63, wave = tid >> 6;
  const int la = lane & 15, lb = lane >> 4;
  const int f0 = blockIdx.x * 64;
  const int k0 = blockIdx.y * 4096;

  f32x4 acc[4];
#pragma unroll
  for (int i = 0; i < 4; ++i) acc[i] = (f32x4){0.f, 0.f, 0.f, 0.f};

  const ushort_t* xrow[2];
#pragma unroll
  for (int s = 0; s < 2; ++s) {
    int idx = tid + (s << 8);
    xrow[s] = Xf + (size_t)(idx >> 3) * KFC + k0 + (idx & 7) * 8;
  }
  const int brow = tid >> 2, kseg = (tid & 3) * 16;
  const float* wrow = Wf1 + (size_t)(f0 + brow) * KFC + k0 + kseg;

  for (int kc = 0; kc < 4096; kc += 64) {
#pragma unroll
    for (int s = 0; s < 2; ++s) {
      int idx = tid + (s << 8);
      gl_lds16(xrow[s] + kc, &As[idx * 8]);
    }
    float4 w0 = *(const float4*)(wrow + kc);
    float4 w1 = *(const float4*)(wrow + kc + 4);
    float4 w2 = *(const float4*)(wrow + kc + 8);
    float4 w3 = *(const float4*)(wrow + kc + 12);
    *(u16x8*)&Bs[brow * 64 + kseg]     = pack8(w0, w1);
    *(u16x8*)&Bs[brow * 64 + kseg + 8] = pack8(w2, w3);
    __syncthreads();
#pragma unroll
    for (int kk = 0; kk < 2; ++kk) {
      bf16x8 bfv = *(const bf16x8*)&Bs[(wave * 16 + la) * 64 + kk * 32 + lb * 8];
#pragma unroll
      for (int mi = 0; mi < 4; ++mi) {
        bf16x8 av = *(const bf16x8*)&As[(mi * 16 + la) * 64 + kk * 32 + lb * 8];
        acc[mi] = mfma16(av, bfv, acc[mi]);
      }
    }
    __syncthreads();
  }

  float* slice = hacc + (size_t)blockIdx.y * NB * NF;
#pragma unroll
  for (int mi = 0; mi < 4; ++mi) {
    int row = mi * 16 + lb * 4;
#pragma unroll
    for (int r = 0; r < 4; ++r)
      slice[(size_t)(row + r) * NF + f0 + wave * 16 + la] = acc[mi][r];
  }
}

// ---------------------------------------------------------------------------
// FC2 + bias/relu; sums the 32 fc1 k-slices. grid 64, block 256.
// ---------------------------------------------------------------------------
__global__ __launch_bounds__(256) void fc2_out(
    const float* __restrict__ hacc, const float* __restrict__ bf1,
    const float* __restrict__ Wf2, const float* __restrict__ bf2,
    float* __restrict__ out)
{
  const int b = blockIdx.x, tid = threadIdx.x;
  float a[8];
#pragma unroll
  for (int o = 0; o < 8; ++o) a[o] = 0.f;
  for (int f = tid; f < NF; f += 256) {
    float hv = bf1[f];
#pragma unroll 4
    for (int s = 0; s < KSPL; ++s)
      hv += hacc[((size_t)s * NB + b) * NF + f];
    hv = fmaxf(hv, 0.f);
#pragma unroll
    for (int o = 0; o < 8; ++o) a[o] += hv * Wf2[o * NF + f];
  }
  __shared__ float red[8][256];
#pragma unroll
  for (int o = 0; o < 8; ++o) red[o][tid] = a[o];
  __syncthreads();
  for (int s = 128; s > 0; s >>= 1) {
    if (tid < s) {
#pragma unroll
      for (int o = 0; o < 8; ++o) red[o][tid] += red[o][tid + s];
    }
    __syncthreads();
  }
  if (tid < 8) out[b * 8 + tid] = red[tid][0] + bf2[tid];
}

// ---------------------------------------------------------------------------
extern "C" void kernel_launch(void* const* d_in, const int* in_sizes, int n_in,
                              void* d_out, int out_size, void* d_ws, size_t ws_size,
                              hipStream_t stream) {
  const float* f1  = (const float*)d_in[0];
  const float* f2  = (const float*)d_in[1];
  const float* W1  = (const float*)d_in[2];
  const float* b1  = (const float*)d_in[3];
  const float* g1  = (const float*)d_in[4];
  const float* be1 = (const float*)d_in[5];
  const float* W2  = (const float*)d_in[6];
  const float* b2  = (const float*)d_in[7];
  const float* g2  = (const float*)d_in[8];
  const float* be2 = (const float*)d_in[9];
  const float* W3  = (const float*)d_in[10];
  const float* b3  = (const float*)d_in[11];
  const float* g3  = (const float*)d_in[12];
  const float* be3 = (const float*)d_in[13];
  const float* Wf1 = (const float*)d_in[14];
  const float* bf1 = (const float*)d_in[15];
  const float* Wf2 = (const float*)d_in[16];
  const float* bf2 = (const float*)d_in[17];
  float* out = (float*)d_out;

  char* ws = (char*)d_ws;
  size_t off = 0;
  auto alloc = [&](size_t bytes) -> void* {
    void* p = ws + off;
    off += (bytes + 255) & ~(size_t)255;
    return p;
  };

  // zeroed region: zero tile + BN stats
  ushort_t* zerot = (ushort_t*)alloc(256);
  float* st1  = (float*)alloc(1024 * 4);
  float* st2  = (float*)alloc(1024 * 4);
  float* st3  = (float*)alloc(1024 * 4);
  const size_t zero_bytes = off;

  float* hacc = (float*)alloc((size_t)KSPL * NB * NF * 4);  // fully written
  const size_t SZ_AT   = (size_t)NB * NP * NC * 2;
  const size_t SZ_COST = (size_t)NB * NP * KP1 * 2;
  const size_t SZ_WP1  = (size_t)9 * NOUT * KP1 * 2;
  const size_t SZ_WP23 = (size_t)9 * NOUT * 512 * 2;
  ushort_t* AT    = (ushort_t*)alloc(SZ_AT);
  ushort_t* N2T   = (ushort_t*)alloc(SZ_AT);
  ushort_t* costT = (ushort_t*)alloc(SZ_COST);
  ushort_t* Wp1   = (ushort_t*)alloc(SZ_WP1);
  ushort_t* Wp2   = (ushort_t*)alloc(SZ_WP23);
  ushort_t* Wp3   = (ushort_t*)alloc(SZ_WP23);
  ushort_t* Yh0   = (ushort_t*)alloc((size_t)NROWS * NOUT * 2);
  ushort_t* Yh1   = (ushort_t*)alloc((size_t)NROWS * NOUT * 2);
  ushort_t* Xbuf  = (ushort_t*)alloc((size_t)NROWS * NOUT * 2);
  ushort_t* Xf    = (ushort_t*)alloc((size_t)NB * KFC * 2);

  hipMemsetAsync(ws, 0, zero_bytes, stream);
  hipMemsetAsync(costT, 0, SZ_COST, stream);

  l2norm_t<<<dim3(64, 2), 256, 0, stream>>>(f1, f2, AT, N2T);

  pack_w<<<(9 * NOUT * KP1 + 255) / 256, 256, 0, stream>>>(W1, Wp1, 1089, KP1, 9 * NOUT * KP1);
  pack_w<<<(9 * NOUT * 512 + 255) / 256, 256, 0, stream>>>(W2, Wp2, 512, 512, 9 * NOUT * 512);
  pack_w<<<(9 * NOUT * 512 + 255) / 256, 256, 0, stream>>>(W3, Wp3, 512, 512, 9 * NOUT * 512);

  cv_gemm<<<dim3(18, 2, 64), 256, 0, stream>>>(AT, N2T, costT, zerot);

  conv_gemm256<<<256, 512, 0, stream>>>(costT, Wp1, b1, Yh0, Yh1, KP1, 18, 81, zerot);
  bn_stat2<<<512, 512, 0, stream>>>(Yh0, Yh1, st1);
  bn_apply2<<<4096, 256, 0, stream>>>(Yh0, Yh1, st1, g1, be1, Xbuf);

  conv_gemm256<<<256, 512, 0, stream>>>(Xbuf, Wp2, b2, Yh0, Yh1, 512, 8, 36, zerot);
  bn_stat2<<<512, 512, 0, stream>>>(Yh0, Yh1, st2);
  bn_apply2<<<4096, 256, 0, stream>>>(Yh0, Yh1, st2, g2, be2, Xbuf);

  conv_gemm256<<<256, 512, 0, stream>>>(Xbuf, Wp3, b3, Yh0, Yh1, 512, 8, 36, zerot);
  bn_stat2<<<512, 512, 0, stream>>>(Yh0, Yh1, st3);
  bn_apply2_t<<<dim3(8, 4, 64), 256, 0, stream>>>(Yh0, Yh1, st3, g3, be3, Xf);

  fc1_gemm<<<dim3(16, KSPL), 256, 0, stream>>>(Xf, Wf1, hacc);
  fc2_out<<<64, 256, 0, stream>>>(hacc, bf1, Wf2, bf2, out);

  (void)in_sizes; (void)n_in; (void)out_size; (void)ws_size;
}